// Round 2
// baseline (220.377 us; speedup 1.0000x reference)
//
#include <hip/hip_runtime.h>
#include <hip/hip_bf16.h>

typedef __hip_bfloat16 BF16;
typedef __attribute__((ext_vector_type(8))) short short8;
typedef __attribute__((ext_vector_type(4))) short short4v;
typedef __attribute__((ext_vector_type(4))) float f32x4;

#define MFMA_B16(a,b,c) __builtin_amdgcn_mfma_f32_16x16x32_bf16((a),(b),(c),0,0,0)

#if __has_builtin(__builtin_amdgcn_exp2f)
#define EXP2F(x) __builtin_amdgcn_exp2f(x)
#else
#define EXP2F(x) __expf(0.6931471805599453f * (x))
#endif

__device__ __forceinline__ short f2bs(float f){ BF16 h = __float2bfloat16(f); return *(short*)&h; }
__device__ __forceinline__ float bs2f(short s){ BF16 h = *(BF16*)&s; return __bfloat162float(h); }

// ---------- prep: transpose+split 10 f32 weight mats to n-major bf16 hi/lo, ----------
// ---------- plus elementwise hi/lo split of x (row-major) for the fc GEMM    ----------
struct SrcPack { const float* s[10]; };

__global__ __launch_bounds__(256) void prep_k(SrcPack p, const float* __restrict__ X,
                                              short* __restrict__ Oh,
                                              short* __restrict__ Ol,
                                              short* __restrict__ Xh,
                                              short* __restrict__ Xl)
{
    if (blockIdx.y >= 10) {
        // x split: 64 blocks x 16384 f32 each, fully coalesced
        int u = (blockIdx.y - 10) * 16 + blockIdx.x;     // 0..63
        size_t base = (size_t)u * 16384;
        #pragma unroll
        for (int i = 0; i < 16; i++) {
            size_t idx = base + (size_t)i * 1024 + threadIdx.x * 4;
            float4 f = *(const float4*)(X + idx);
            short4v vh, vl;
            float t0[4] = {f.x, f.y, f.z, f.w};
            #pragma unroll
            for (int j = 0; j < 4; j++) {
                vh[j] = f2bs(t0[j]);
                vl[j] = f2bs(t0[j] - bs2f(vh[j]));
            }
            *(short4v*)(Xh + idx) = vh;
            *(short4v*)(Xl + idx) = vl;
        }
        return;
    }
    __shared__ float s[64][65];
    const float* W = p.s[blockIdx.y];
    short* oh = Oh + (size_t)blockIdx.y * 65536;
    short* ol = Ol + (size_t)blockIdx.y * 65536;
    int tr = (blockIdx.x >> 2) * 64, tc = (blockIdx.x & 3) * 64;
    #pragma unroll
    for (int i = 0; i < 16; i++) {
        int e = threadIdx.x + i * 256;
        int r = e >> 6, c = e & 63;
        s[c][r] = W[(size_t)(tr + r) * 256 + tc + c];
    }
    __syncthreads();
    #pragma unroll
    for (int i = 0; i < 16; i++) {
        int e = threadIdx.x + i * 256;
        int c2 = e >> 6, r2 = e & 63;
        float v = s[c2][r2];
        short hi = f2bs(v);
        short lo = f2bs(v - bs2f(hi));
        size_t oi = (size_t)(tc + c2) * 256 + tr + r2;
        oh[oi] = hi;
        ol[oi] = lo;
    }
}

// ---------- generic MFMA GEMM body, split-bf16 precision ----------
// AM: 0 = A single bf16 plane, 2 = A dual bf16 planes.
// OM: 0 = f32, 1 = bf16.  BS: 1 = single-plane B (Wl unused).
// LDK = 72 shorts: 16B-aligned short8 rows (odd pads break b128).
template<int AM, int OM, int RELU, int BS>
__device__ __forceinline__ void gemm_body(const void* __restrict__ A0,
    const void* __restrict__ Alo,
    const short* __restrict__ Wh, const short* __restrict__ Wl,
    const float* __restrict__ bias, void* __restrict__ O0,
    int row0, int col0)
{
    constexpr int LDK = 72;
    __shared__ short sAh[64 * LDK];
    __shared__ short sAl[(AM == 0) ? 8 : 64 * LDK];
    __shared__ short sBh[64 * LDK];
    __shared__ short sBl[BS ? 8 : 64 * LDK];
    int tid = threadIdx.x;
    int w = tid >> 6, l = tid & 63;
    int m = l & 15, q = l >> 4;
    int sr = w * 16 + m;

    f32x4 acc[4];
    #pragma unroll
    for (int cf = 0; cf < 4; cf++) acc[cf] = (f32x4)(0.f);

    for (int kh = 0; kh < 4; kh++) {
        int kbase = kh * 64;
        #pragma unroll
        for (int i = 0; i < 2; i++) {
            int kl = q * 8 + 32 * i;
            size_t gofs = (size_t)(row0 + sr) * 256 + kbase + kl;
            if (AM == 2) {
                *(short8*)&sAh[sr * LDK + kl] = *(const short8*)((const short*)A0 + gofs);
                *(short8*)&sAl[sr * LDK + kl] = *(const short8*)((const short*)Alo + gofs);
            } else {
                *(short8*)&sAh[sr * LDK + kl] = *(const short8*)((const short*)A0 + gofs);
            }
            size_t gofsB = (size_t)(col0 + sr) * 256 + kbase + kl;
            *(short8*)&sBh[sr * LDK + kl] = *(const short8*)(Wh + gofsB);
            if (!BS)
                *(short8*)&sBl[sr * LDK + kl] = *(const short8*)(Wl + gofsB);
        }
        __syncthreads();
        #pragma unroll
        for (int ch = 0; ch < 2; ch++) {
            int k = ch * 32 + q * 8;
            short8 ah = *(const short8*)&sAh[(w * 16 + m) * LDK + k];
            short8 al = (AM != 0) ? *(const short8*)&sAl[(w * 16 + m) * LDK + k] : ah;
            #pragma unroll
            for (int cf = 0; cf < 4; cf++) {
                short8 bh = *(const short8*)&sBh[(cf * 16 + m) * LDK + k];
                acc[cf] = MFMA_B16(ah, bh, acc[cf]);
                if (!BS) {
                    short8 bl = *(const short8*)&sBl[(cf * 16 + m) * LDK + k];
                    acc[cf] = MFMA_B16(ah, bl, acc[cf]);
                }
                if (AM != 0)
                    acc[cf] = MFMA_B16(al, bh, acc[cf]);
            }
        }
        __syncthreads();
    }
    // C/D layout: col = lane&15, row = (lane>>4)*4 + reg (m89-verified)
    #pragma unroll
    for (int cf = 0; cf < 4; cf++) {
        int col = col0 + cf * 16 + m;
        float bv = bias ? bias[col] : 0.f;
        #pragma unroll
        for (int r = 0; r < 4; r++) {
            int row = row0 + w * 16 + q * 4 + r;
            float v = acc[cf][r] + bv;
            if (RELU) v = fmaxf(v, 0.f);
            size_t oi = (size_t)row * 256 + col;
            if (OM == 0) {
                ((float*)O0)[oi] = v;
            } else {
                ((short*)O0)[oi] = f2bs(v);
            }
        }
    }
}

// batched-direction generic GEMM
struct GDir { const void* A0; const void* Al; const short* Wh; const short* Wl;
              const float* bias; void* O0; };

template<int AM, int OM, int RELU, int BS>
__global__ __launch_bounds__(256) void gemm_k(GDir p0, GDir p1)
{
    GDir p = blockIdx.z ? p1 : p0;
    gemm_body<AM, OM, RELU, BS>(p.A0, p.Al, p.Wh, p.Wl, p.bias, p.O0,
                                blockIdx.x * 64, blockIdx.y * 64);
}

// ---------- fused dual mSA-GEMM + level-1 masked attention, 512 threads ----------
// Grid (bn, dchunk, dir) = 512 blocks (parity merge: each block computes the
// 64x64 P/Q tile ONCE and runs the tail for all 64 rows; wave w covers rows
// w+8t). 33.5 KB LDS -> 2 blk/CU resident (16 waves/CU).
//   P' = exp(0.4A)*(-ln2/10); w = exp2(rcp(fma(P',q,-ln2/10))) = exp(-10/(1+u)).
struct MbloDir { const short* Ah;
                 const short* W1h; const short* W2h;
                 const float* mb; short* Hh; int fw; };

__global__ __launch_bounds__(512) void mblo_k(MbloDir p0, MbloDir p1)
{
    __shared__ char smraw[33536] __attribute__((aligned(16)));
    short* gAh  = (short*)smraw;            // 64*72 shorts each (GEMM phase)
    short* gB1h = gAh + 4608;
    short* gB2h = gAh + 9216;
    float* aP   = (float*)smraw;            // [i*66 + l] P' (tail overlay, 16.9 KB)
    unsigned int* aQX = (unsigned int*)(smraw + 16896); // [d*65 + j]: lo=Q bf16, hi=X bf16

    const float KLN = -0.06931471805599453f;   // -ln2/10

    MbloDir p = blockIdx.z ? p1 : p0;
    int tid = threadIdx.x;
    int w = tid >> 6, l = tid & 63;
    int m = l & 15, q = l >> 4;
    int rh = w >> 1;            // row strip 0..3
    int cb = (w & 1) * 2;       // col-frag base: 0 or 2
    int row0 = blockIdx.x * 64, d0 = blockIdx.y * 64;
    int srow = tid >> 3;        // staging row 0..63
    int skl  = (tid & 7) * 8;   // staging k offset

    f32x4 acc1[2], acc2[2];
    #pragma unroll
    for (int cf = 0; cf < 2; cf++) { acc1[cf] = (f32x4)(0.f); acc2[cf] = (f32x4)(0.f); }

    for (int kh = 0; kh < 4; kh++) {
        int kbase = kh * 64;
        size_t ga = (size_t)(row0 + srow) * 256 + kbase + skl;
        *(short8*)&gAh[srow * 72 + skl] = *(const short8*)(p.Ah + ga);
        size_t gb = (size_t)(d0 + srow) * 256 + kbase + skl;
        *(short8*)&gB1h[srow * 72 + skl] = *(const short8*)(p.W1h + gb);
        *(short8*)&gB2h[srow * 72 + skl] = *(const short8*)(p.W2h + gb);
        __syncthreads();
        #pragma unroll
        for (int ch = 0; ch < 2; ch++) {
            int k = ch * 32 + q * 8;
            short8 ah = *(const short8*)&gAh[(rh * 16 + m) * 72 + k];
            #pragma unroll
            for (int cf = 0; cf < 2; cf++) {
                int bofs = ((cb + cf) * 16 + m) * 72 + k;
                short8 b1 = *(const short8*)&gB1h[bofs];
                acc1[cf] = MFMA_B16(ah, b1, acc1[cf]);
                short8 b2 = *(const short8*)&gB2h[bofs];
                acc2[cf] = MFMA_B16(ah, b2, acc2[cf]);
            }
        }
        __syncthreads();   // also guards the union overwrite below
    }
    // epilogue: P' row-major f32; Q bf16 into low half of packed QX word
    short* sQX = (short*)aQX;
    #pragma unroll
    for (int cf = 0; cf < 2; cf++) {
        int col = (cb + cf) * 16 + m;        // d index
        float mbv = p.mb[d0 + col];
        #pragma unroll
        for (int r = 0; r < 4; r++) {
            int row = rh * 16 + q * 4 + r;   // j index
            aP[row * 66 + col] = __expf(0.4f * acc1[cf][r]) * KLN;
            sQX[col * 130 + 2 * row] = f2bs(__expf(0.4f * (acc2[cf][r] + mbv)));
        }
    }
    {   // X tile (bf16 hi plane, raw copy) into high halves
        size_t gx = (size_t)(row0 + srow) * 256 + d0 + skl;
        short8 xh = *(const short8*)(p.Ah + gx);
        #pragma unroll
        for (int t = 0; t < 8; t++)
            sQX[(skl + t) * 130 + 2 * srow + 1] = xh[t];
    }
    __syncthreads();
    // masked attention: wave w handles rows {w + 8t}, t<8
    const unsigned int* lane_qx = &aQX[l * 65];
    for (int t8 = 0; t8 < 8; t8++) {
        int i = w + 8 * t8;
        float Pp = aP[i * 66 + l];
        int js = p.fw ? (i + 1) : 0;
        int je = p.fw ? 64 : i;
        float den0 = 0.f, den1 = 0.f, num0 = 0.f, num1 = 0.f;
        int j = js;
        for (; j + 4 <= je; j += 4) {
            unsigned int u0 = lane_qx[j];
            unsigned int u1 = lane_qx[j + 1];
            unsigned int u2 = lane_qx[j + 2];
            unsigned int u3 = lane_qx[j + 3];
            float q0 = bs2f((short)(u0 & 0xffff)), x0 = bs2f((short)(u0 >> 16));
            float q1 = bs2f((short)(u1 & 0xffff)), x1 = bs2f((short)(u1 >> 16));
            float q2 = bs2f((short)(u2 & 0xffff)), x2 = bs2f((short)(u2 >> 16));
            float q3 = bs2f((short)(u3 & 0xffff)), x3 = bs2f((short)(u3 >> 16));
            float w0 = EXP2F(__builtin_amdgcn_rcpf(fmaf(Pp, q0, KLN)));
            float w1 = EXP2F(__builtin_amdgcn_rcpf(fmaf(Pp, q1, KLN)));
            float w2 = EXP2F(__builtin_amdgcn_rcpf(fmaf(Pp, q2, KLN)));
            float w3 = EXP2F(__builtin_amdgcn_rcpf(fmaf(Pp, q3, KLN)));
            den0 += w0; num0 = fmaf(w0, x0, num0);
            den1 += w1; num1 = fmaf(w1, x1, num1);
            den0 += w2; num0 = fmaf(w2, x2, num0);
            den1 += w3; num1 = fmaf(w3, x3, num1);
        }
        for (; j < je; j++) {
            unsigned int u0 = lane_qx[j];
            float q0 = bs2f((short)(u0 & 0xffff)), x0 = bs2f((short)(u0 >> 16));
            float wgt = EXP2F(__builtin_amdgcn_rcpf(fmaf(Pp, q0, KLN)));
            den0 += wgt; num0 = fmaf(wgt, x0, num0);
        }
        float den = den0 + den1, num = num0 + num1;
        bool valid = p.fw ? (i < 63) : (i > 0);
        float out = valid ? (num * __builtin_amdgcn_rcpf(den)) : 0.f;
        p.Hh[(size_t)(row0 + i) * 256 + d0 + l] = f2bs(out);
    }
}

// ---------- fused s2t: T1 = relu(h@W3+b1) in LDS, then L = T1@W4+b + softmax pool ----
// Grid (64 groups, 4 dchunk, 2 dir) = 1024 blocks, 512 threads. Phase 1 computes
// the full 64x256 T1 tile (4x redundant across d-chunks - aggregate MFMA cost is
// ~2 us, irrelevant; keeps LDS-resident T1 with rounding identical to the old t1
// global round trip). Phase 2: single 64-col chunk of L + pool (h read direct
// from global, L2-hot). LDS 78 KB -> 2 blk/CU, 16 waves/CU.
struct S2TDir { const short* Hh; const short* W3h; const float* b1;
                const short* W4h; const float* b2; float* V; };

__global__ __launch_bounds__(512) void s2t_fused_k(S2TDir p0, S2TDir p1)
{
    __shared__ char smraw[79872] __attribute__((aligned(16)));
    short* sT1 = (short*)smraw;                 // [64][264] bf16, persists (33792 B)
    short* gA  = (short*)(smraw + 33792);       // phase-1 A stage 64*72   (9216 B)
    short* gB  = (short*)(smraw + 43008);       // phase-1 B stage 256*72  (36864 B)
    short* gB2 = (short*)(smraw + 33792);       // phase-2 B stage 64*72 (overlay gA)
    float* aL  = (float*)(smraw + 43008);       // [64][68] f32 logits (overlay gB)
    float* rm  = (float*)(smraw + 60416);       // 8*64 partial max
    float* rd  = rm + 512;                      // 8*64 partial den
    float* rn  = rm + 1024;                     // 8*64 partial num

    S2TDir p = blockIdx.z ? p1 : p0;
    int tid = threadIdx.x;
    int w = tid >> 6, l = tid & 63;
    int m = l & 15, q = l >> 4;
    int row0 = blockIdx.x * 64;
    int d0 = blockIdx.y * 64;
    int strip = w >> 1, chalf = w & 1;          // wave -> (row strip, col half)
    int srow = tid >> 3, skl = (tid & 7) * 8;   // 64-row staging map

    // ---- phase 1: T1 full 64x256 ----
    f32x4 acc1[8];
    #pragma unroll
    for (int cf = 0; cf < 8; cf++) acc1[cf] = (f32x4)(0.f);
    for (int kh = 0; kh < 4; kh++) {
        int kbase = kh * 64;
        *(short8*)&gA[srow * 72 + skl] =
            *(const short8*)(p.Hh + (size_t)(row0 + srow) * 256 + kbase + skl);
        int bn = tid >> 1;
        #pragma unroll
        for (int i = 0; i < 4; i++) {
            int kseg = (tid & 1) * 32 + i * 8;
            *(short8*)&gB[bn * 72 + kseg] =
                *(const short8*)(p.W3h + (size_t)bn * 256 + kbase + kseg);
        }
        __syncthreads();
        #pragma unroll
        for (int ch = 0; ch < 2; ch++) {
            int k = ch * 32 + q * 8;
            short8 ah = *(const short8*)&gA[(strip * 16 + m) * 72 + k];
            #pragma unroll
            for (int cf = 0; cf < 8; cf++) {
                short8 bh = *(const short8*)&gB[(chalf * 128 + cf * 16 + m) * 72 + k];
                acc1[cf] = MFMA_B16(ah, bh, acc1[cf]);
            }
        }
        __syncthreads();
    }
    #pragma unroll
    for (int cf = 0; cf < 8; cf++) {
        int col = chalf * 128 + cf * 16 + m;
        float bv = p.b1[col];
        #pragma unroll
        for (int r = 0; r < 4; r++) {
            int row = strip * 16 + q * 4 + r;
            sT1[row * 264 + col] = f2bs(fmaxf(acc1[cf][r] + bv, 0.f));
        }
    }
    __syncthreads();

    // ---- phase 2: one 64-col chunk of L + pool ----
    f32x4 acc2[2];
    acc2[0] = (f32x4)(0.f); acc2[1] = (f32x4)(0.f);
    for (int kh = 0; kh < 4; kh++) {
        int kbase = kh * 64;
        *(short8*)&gB2[srow * 72 + skl] =
            *(const short8*)(p.W4h + (size_t)(d0 + srow) * 256 + kbase + skl);
        __syncthreads();
        #pragma unroll
        for (int ch = 0; ch < 2; ch++) {
            int k = ch * 32 + q * 8;
            short8 ah = *(const short8*)&sT1[(strip * 16 + m) * 264 + kbase + k];
            #pragma unroll
            for (int cf = 0; cf < 2; cf++) {
                short8 bh = *(const short8*)&gB2[(chalf * 32 + cf * 16 + m) * 72 + k];
                acc2[cf] = MFMA_B16(ah, bh, acc2[cf]);
            }
        }
        __syncthreads();
    }
    #pragma unroll
    for (int cf = 0; cf < 2; cf++) {
        int col = chalf * 32 + cf * 16 + m;
        float bv = p.b2[d0 + col];
        #pragma unroll
        for (int r = 0; r < 4; r++) {
            int row = strip * 16 + q * 4 + r;
            aL[row * 68 + col] = acc2[cf][r] + bv;
        }
    }
    __syncthreads();
    int dl = tid & 63, rq = tid >> 6;       // 8 row-chunks of 8
    float mx = -1e30f, den = 0.f, num = 0.f;
    #pragma unroll
    for (int rr = 0; rr < 8; rr++) {
        int r = rq * 8 + rr;
        float lv = aL[r * 68 + dl];
        float hv = bs2f(p.Hh[(size_t)(row0 + r) * 256 + d0 + dl]);
        if (lv > mx) { float sc = __expf(mx - lv); den *= sc; num *= sc; mx = lv; }
        float wgt = __expf(lv - mx);
        den += wgt; num = fmaf(wgt, hv, num);
    }
    rm[rq * 64 + dl] = mx; rd[rq * 64 + dl] = den; rn[rq * 64 + dl] = num;
    __syncthreads();
    if (rq == 0) {
        float M = rm[dl];
        #pragma unroll
        for (int kq = 1; kq < 8; kq++) M = fmaxf(M, rm[kq * 64 + dl]);
        float D = 0.f, Nn = 0.f;
        #pragma unroll
        for (int kq = 0; kq < 8; kq++) {
            float sc = __expf(rm[kq * 64 + dl] - M);
            D += rd[kq * 64 + dl] * sc;
            Nn += rn[kq * 64 + dl] * sc;
        }
        p.V[(size_t)blockIdx.x * 256 + d0 + dl] = Nn / D;
    }
}

// ---------- fused level-2 attention (row 0) + gate, with inline vW1/vW2 GEMV ----
// 1024 threads, grid (4 b, 4 ychunk, 2 dir). fw blocks compute the 16 rows of
// v@mW1 / v@mW2 the attention reads as f32 register GEMVs over the RAW weights,
// kk-range 4-way split across thread quarters (64 serial iters) with an LDS
// reduce. Then tanh-softmax attention + gate GEMM (16-way k-split).
struct Gate2Dir { const float* V; const float* W1; const float* W2; const float* mb;
                  const float* gW1; const float* gW2; const float* gb;
                  float* E0; int fw; };

__global__ __launch_bounds__(1024) void attn2gate_k(Gate2Dir p0, Gate2Dir p1)
{
    Gate2Dir p = blockIdx.z ? p1 : p0;
    __shared__ __attribute__((aligned(16))) float sVT[4096];   // [kk*16+j] = v[b16+j][kk]
    __shared__ float sPart[3][16][256];
    __shared__ float so[256], sv[256], red[16][64];
    int tid = threadIdx.x;
    int b = blockIdx.x;
    int k = tid & 255, quarter = tid >> 8;

    if (p.fw) {
        #pragma unroll
        for (int it = 0; it < 4; it++) {
            int e = tid + it * 1024;
            int kk = e >> 4, j = e & 15;
            sVT[e] = p.V[(size_t)(b * 16 + j) * 256 + kk];
        }
        __syncthreads();
        float acc[16];
        #pragma unroll
        for (int j = 0; j < 16; j++) acc[j] = 0.f;
        int kk0 = quarter * 64;
        #pragma unroll 4
        for (int kk = kk0; kk < kk0 + 64; kk++) {
            const float4* vr = (const float4*)&sVT[kk * 16];
            float4 va = vr[0], vb = vr[1], vc = vr[2], vd = vr[3];
            float w1 = p.W1[(size_t)kk * 256 + k];
            float w2 = p.W2[(size_t)kk * 256 + k];
            acc[0]  = fmaf(va.x, w1, acc[0]);
            acc[1]  = fmaf(va.y, w2, acc[1]);
            acc[2]  = fmaf(va.z, w2, acc[2]);
            acc[3]  = fmaf(va.w, w2, acc[3]);
            acc[4]  = fmaf(vb.x, w2, acc[4]);
            acc[5]  = fmaf(vb.y, w2, acc[5]);
            acc[6]  = fmaf(vb.z, w2, acc[6]);
            acc[7]  = fmaf(vb.w, w2, acc[7]);
            acc[8]  = fmaf(vc.x, w2, acc[8]);
            acc[9]  = fmaf(vc.y, w2, acc[9]);
            acc[10] = fmaf(vc.z, w2, acc[10]);
            acc[11] = fmaf(vc.w, w2, acc[11]);
            acc[12] = fmaf(vd.x, w2, acc[12]);
            acc[13] = fmaf(vd.y, w2, acc[13]);
            acc[14] = fmaf(vd.z, w2, acc[14]);
            acc[15] = fmaf(vd.w, w2, acc[15]);
        }
        if (quarter) {
            #pragma unroll
            for (int j = 0; j < 16; j++) sPart[quarter - 1][j][k] = acc[j];
        }
        __syncthreads();
        if (!quarter) {
            #pragma unroll
            for (int j = 0; j < 16; j++)
                acc[j] += sPart[0][j][k] + sPart[1][j][k] + sPart[2][j][k];
            float base = acc[0] + p.mb[k];          // qv + mb
            float den = 0.f, num = 0.f;
            #pragma unroll
            for (int j = 1; j < 16; j++) {
                float z = (base + acc[j]) * 0.2f;
                float e2 = __expf(2.f * z);
                float t = 1.f - 2.f / (e2 + 1.f);
                float wgt = __expf(5.f * t);
                den += wgt;
                num = fmaf(wgt, p.V[(size_t)(b * 16 + j) * 256 + k], num);
            }
            so[k] = num / den;
            sv[k] = p.V[(size_t)(b * 16) * 256 + k];
        }
    } else {
        if (tid < 256) {
            so[k] = 0.f;
            sv[k] = p.V[(size_t)(b * 16) * 256 + k];
        }
    }
    __syncthreads();
    int c = tid & 63, ks = tid >> 6;           // 16-way k-split
    int gc = blockIdx.y * 64 + c;
    float a2 = 0.f;
    int k0 = ks * 16;
    #pragma unroll
    for (int kkx = 0; kkx < 16; kkx++) {
        int kx = k0 + kkx;
        a2 += so[kx] * p.gW1[(size_t)kx * 256 + gc] + sv[kx] * p.gW2[(size_t)kx * 256 + gc];
    }
    red[ks][c] = a2;
    __syncthreads();
    if (ks == 0) {
        float a = p.gb[gc];
        #pragma unroll
        for (int kq = 0; kq < 16; kq++) a += red[kq][c];
        float G = 1.f / (1.f + __expf(-a));
        p.E0[b * 256 + gc] = G * so[gc] + (1.f - G) * sv[gc];
    }
}

// ---------- fusion: grid (64 bt, 4 dchunk, 2 dir), split-K(4x192) x 64-col ----------
struct FuseDir { const short* INh; const short* Hh;
                 const float* E0; const float* fW1; const float* fb1;
                 const float* fW2; const float* fb2; };

__global__ __launch_bounds__(256) void fusion_k(FuseDir p0, FuseDir p1, float* __restrict__ out)
{
    FuseDir p = blockIdx.z ? p1 : p0;
    __shared__ float cat[768];
    __shared__ float red1[4][64], red2[4][64];
    int bt = blockIdx.x, b = bt >> 4, t = bt & 15;
    int c = threadIdx.x & 63, ks = threadIdx.x >> 6;
    int gc = blockIdx.y * 64 + c;
    size_t xrow = ((size_t)b * 1024 + t) * 256;   // (b, n=0, r=t)
    cat[threadIdx.x]       = bs2f(p.INh[xrow + threadIdx.x]);
    cat[256 + threadIdx.x] = bs2f(p.Hh[xrow + threadIdx.x]);
    cat[512 + threadIdx.x] = p.E0[b * 256 + threadIdx.x];
    __syncthreads();
    float a1 = 0.f, a2 = 0.f;
    int k0 = ks * 192;
    #pragma unroll 8
    for (int kk = 0; kk < 192; kk++) {
        int k = k0 + kk;
        float cv = cat[k];
        a1 += cv * p.fW1[(size_t)k * 256 + gc];
        a2 += cv * p.fW2[(size_t)k * 256 + gc];
    }
    red1[ks][c] = a1; red2[ks][c] = a2;
    __syncthreads();
    if (ks == 0) {
        float s1 = red1[0][c] + red1[1][c] + red1[2][c] + red1[3][c] + p.fb1[gc];
        float s2 = red2[0][c] + red2[1][c] + red2[2][c] + red2[3][c] + p.fb2[gc];
        float fus = fmaxf(s1, 0.f);
        float Gf = 1.f / (1.f + __expf(-s2));
        float u = Gf * fus + (1.f - Gf) * cat[gc];
        out[((size_t)(b * 16 + t)) * 512 + (size_t)blockIdx.z * 256 + gc] = u;
    }
}

extern "C" void kernel_launch(void* const* d_in, const int* in_sizes, int n_in,
                              void* d_out, int out_size, void* d_ws, size_t ws_size,
                              hipStream_t stream)
{
    const float* x = (const float*)d_in[0];
    char* base = (char*)d_ws;
    auto alloc = [&](size_t bytes){ void* r = base; base += (bytes + 255) & ~255ULL; return r; };
    short* inH = (short*)alloc(2 * 1048576 * 2);
    short* hH  = (short*)alloc(2 * 1048576 * 2);
    short* wtH = (short*)alloc(10 * 65536 * 2);
    short* wtL = (short*)alloc(10 * 65536 * 2);
    short* xh  = (short*)alloc(1048576 * 2);
    short* xl  = (short*)alloc(1048576 * 2);
    float* v   = (float*)alloc(2 * 16384 * 4);
    float* E0  = (float*)alloc(2 * 1024 * 4);

    SrcPack sp;
    const int src_idx[5] = {0, 2, 3, 5, 7};  // fcW, mW1, mW2, s2tW1, s2tW
    for (int p = 0; p < 2; p++)
        for (int i = 0; i < 5; i++)
            sp.s[p * 5 + i] = (const float*)d_in[1 + p * 16 + src_idx[i]];
    prep_k<<<dim3(16, 14), 256, 0, stream>>>(sp, x, wtH, wtL, xh, xl);

    GDir fc[2];
    MbloDir mbd[2];
    S2TDir std_[2];
    Gate2Dir gtd[2];
    FuseDir fsd[2];
    for (int p = 0; p < 2; p++) {
        int bi = 1 + p * 16;
        const float* fcb   = (const float*)d_in[bi + 1];
        const float* mb    = (const float*)d_in[bi + 4];
        const float* s2tb1 = (const float*)d_in[bi + 6];
        const float* s2tb  = (const float*)d_in[bi + 8];
        size_t po = (size_t)p * 1048576;
        const short* W0h = wtH + (size_t)(p * 5 + 0) * 65536, *W0l = wtL + (size_t)(p * 5 + 0) * 65536;
        const short* W1h = wtH + (size_t)(p * 5 + 1) * 65536;
        const short* W2h = wtH + (size_t)(p * 5 + 2) * 65536;
        const short* W3h = wtH + (size_t)(p * 5 + 3) * 65536;
        const short* W4h = wtH + (size_t)(p * 5 + 4) * 65536;

        fc[p]   = { xh, xl, W0h, W0l, fcb, inH + po };
        mbd[p]  = { inH + po, W1h, W2h, mb, hH + po, (p == 0) };
        std_[p] = { hH + po, W3h, s2tb1, W4h, s2tb, v + p * 16384 };
        gtd[p]  = { v + p * 16384,
                    (const float*)d_in[bi + 2], (const float*)d_in[bi + 3], mb,
                    (const float*)d_in[bi + 9], (const float*)d_in[bi + 10],
                    (const float*)d_in[bi + 11], E0 + p * 1024, (p == 0) };
        fsd[p]  = { inH + po, hH + po, E0 + p * 1024,
                    (const float*)d_in[bi + 12], (const float*)d_in[bi + 13],
                    (const float*)d_in[bi + 14], (const float*)d_in[bi + 15] };
    }

    gemm_k<2, 1, 1, 0><<<dim3(64, 4, 2), 256, 0, stream>>>(fc[0], fc[1]);
    mblo_k<<<dim3(64, 4, 2), 512, 0, stream>>>(mbd[0], mbd[1]);
    s2t_fused_k<<<dim3(64, 4, 2), 512, 0, stream>>>(std_[0], std_[1]);
    attn2gate_k<<<dim3(4, 4, 2), 1024, 0, stream>>>(gtd[0], gtd[1]);
    fusion_k<<<dim3(64, 4, 2), 256, 0, stream>>>(fsd[0], fsd[1], (float*)d_out);
}

// Round 3
// 211.416 us; speedup vs baseline: 1.0424x; 1.0424x over previous
//
#include <hip/hip_runtime.h>
#include <hip/hip_bf16.h>

typedef __hip_bfloat16 BF16;
typedef __attribute__((ext_vector_type(8))) short short8;
typedef __attribute__((ext_vector_type(4))) short short4v;
typedef __attribute__((ext_vector_type(4))) float f32x4;

#define MFMA_B16(a,b,c) __builtin_amdgcn_mfma_f32_16x16x32_bf16((a),(b),(c),0,0,0)

#if __has_builtin(__builtin_amdgcn_exp2f)
#define EXP2F(x) __builtin_amdgcn_exp2f(x)
#else
#define EXP2F(x) __expf(0.6931471805599453f * (x))
#endif

__device__ __forceinline__ short f2bs(float f){ BF16 h = __float2bfloat16(f); return *(short*)&h; }
__device__ __forceinline__ float bs2f(short s){ BF16 h = *(BF16*)&s; return __bfloat162float(h); }

// ---------- prep: transpose+split 10 f32 weight mats to n-major bf16 hi/lo, ----------
// ---------- plus elementwise hi/lo split of x (row-major) for the fc GEMM    ----------
struct SrcPack { const float* s[10]; };

__global__ __launch_bounds__(256) void prep_k(SrcPack p, const float* __restrict__ X,
                                              short* __restrict__ Oh,
                                              short* __restrict__ Ol,
                                              short* __restrict__ Xh,
                                              short* __restrict__ Xl)
{
    if (blockIdx.y >= 10) {
        // x split: 64 blocks x 16384 f32 each, fully coalesced
        int u = (blockIdx.y - 10) * 16 + blockIdx.x;     // 0..63
        size_t base = (size_t)u * 16384;
        #pragma unroll
        for (int i = 0; i < 16; i++) {
            size_t idx = base + (size_t)i * 1024 + threadIdx.x * 4;
            float4 f = *(const float4*)(X + idx);
            short4v vh, vl;
            float t0[4] = {f.x, f.y, f.z, f.w};
            #pragma unroll
            for (int j = 0; j < 4; j++) {
                vh[j] = f2bs(t0[j]);
                vl[j] = f2bs(t0[j] - bs2f(vh[j]));
            }
            *(short4v*)(Xh + idx) = vh;
            *(short4v*)(Xl + idx) = vl;
        }
        return;
    }
    __shared__ float s[64][65];
    const float* W = p.s[blockIdx.y];
    short* oh = Oh + (size_t)blockIdx.y * 65536;
    short* ol = Ol + (size_t)blockIdx.y * 65536;
    int tr = (blockIdx.x >> 2) * 64, tc = (blockIdx.x & 3) * 64;
    #pragma unroll
    for (int i = 0; i < 16; i++) {
        int e = threadIdx.x + i * 256;
        int r = e >> 6, c = e & 63;
        s[c][r] = W[(size_t)(tr + r) * 256 + tc + c];
    }
    __syncthreads();
    #pragma unroll
    for (int i = 0; i < 16; i++) {
        int e = threadIdx.x + i * 256;
        int c2 = e >> 6, r2 = e & 63;
        float v = s[c2][r2];
        short hi = f2bs(v);
        short lo = f2bs(v - bs2f(hi));
        size_t oi = (size_t)(tc + c2) * 256 + tr + r2;
        oh[oi] = hi;
        ol[oi] = lo;
    }
}

// ---------- generic MFMA GEMM body, split-bf16 precision ----------
// AM: 0 = A single bf16 plane, 2 = A dual bf16 planes.
// OM: 0 = f32, 1 = bf16.  BS: 1 = single-plane B (Wl unused).
// LDK = 72 shorts: 16B-aligned short8 rows (odd pads break b128).
template<int AM, int OM, int RELU, int BS>
__device__ __forceinline__ void gemm_body(const void* __restrict__ A0,
    const void* __restrict__ Alo,
    const short* __restrict__ Wh, const short* __restrict__ Wl,
    const float* __restrict__ bias, void* __restrict__ O0,
    int row0, int col0)
{
    constexpr int LDK = 72;
    __shared__ short sAh[64 * LDK];
    __shared__ short sAl[(AM == 0) ? 8 : 64 * LDK];
    __shared__ short sBh[64 * LDK];
    __shared__ short sBl[BS ? 8 : 64 * LDK];
    int tid = threadIdx.x;
    int w = tid >> 6, l = tid & 63;
    int m = l & 15, q = l >> 4;
    int sr = w * 16 + m;

    f32x4 acc[4];
    #pragma unroll
    for (int cf = 0; cf < 4; cf++) acc[cf] = (f32x4)(0.f);

    for (int kh = 0; kh < 4; kh++) {
        int kbase = kh * 64;
        #pragma unroll
        for (int i = 0; i < 2; i++) {
            int kl = q * 8 + 32 * i;
            size_t gofs = (size_t)(row0 + sr) * 256 + kbase + kl;
            if (AM == 2) {
                *(short8*)&sAh[sr * LDK + kl] = *(const short8*)((const short*)A0 + gofs);
                *(short8*)&sAl[sr * LDK + kl] = *(const short8*)((const short*)Alo + gofs);
            } else {
                *(short8*)&sAh[sr * LDK + kl] = *(const short8*)((const short*)A0 + gofs);
            }
            size_t gofsB = (size_t)(col0 + sr) * 256 + kbase + kl;
            *(short8*)&sBh[sr * LDK + kl] = *(const short8*)(Wh + gofsB);
            if (!BS)
                *(short8*)&sBl[sr * LDK + kl] = *(const short8*)(Wl + gofsB);
        }
        __syncthreads();
        #pragma unroll
        for (int ch = 0; ch < 2; ch++) {
            int k = ch * 32 + q * 8;
            short8 ah = *(const short8*)&sAh[(w * 16 + m) * LDK + k];
            short8 al = (AM != 0) ? *(const short8*)&sAl[(w * 16 + m) * LDK + k] : ah;
            #pragma unroll
            for (int cf = 0; cf < 4; cf++) {
                short8 bh = *(const short8*)&sBh[(cf * 16 + m) * LDK + k];
                acc[cf] = MFMA_B16(ah, bh, acc[cf]);
                if (!BS) {
                    short8 bl = *(const short8*)&sBl[(cf * 16 + m) * LDK + k];
                    acc[cf] = MFMA_B16(ah, bl, acc[cf]);
                }
                if (AM != 0)
                    acc[cf] = MFMA_B16(al, bh, acc[cf]);
            }
        }
        __syncthreads();
    }
    // C/D layout: col = lane&15, row = (lane>>4)*4 + reg (m89-verified)
    #pragma unroll
    for (int cf = 0; cf < 4; cf++) {
        int col = col0 + cf * 16 + m;
        float bv = bias ? bias[col] : 0.f;
        #pragma unroll
        for (int r = 0; r < 4; r++) {
            int row = row0 + w * 16 + q * 4 + r;
            float v = acc[cf][r] + bv;
            if (RELU) v = fmaxf(v, 0.f);
            size_t oi = (size_t)row * 256 + col;
            if (OM == 0) {
                ((float*)O0)[oi] = v;
            } else {
                ((short*)O0)[oi] = f2bs(v);
            }
        }
    }
}

// batched-direction generic GEMM
struct GDir { const void* A0; const void* Al; const short* Wh; const short* Wl;
              const float* bias; void* O0; };

template<int AM, int OM, int RELU, int BS>
__global__ __launch_bounds__(256) void gemm_k(GDir p0, GDir p1)
{
    GDir p = blockIdx.z ? p1 : p0;
    gemm_body<AM, OM, RELU, BS>(p.A0, p.Al, p.Wh, p.Wl, p.bias, p.O0,
                                blockIdx.x * 64, blockIdx.y * 64);
}

// ---------- fused dual mSA-GEMM + level-1 masked attention, 512 threads ----------
// Grid (bn*2, dchunk, dir) = 1024 blocks (4 blk/CU -> 32 waves/CU, full).
// Sibling blocks (row-parity split) redundantly compute the full 64x64 P/Q tile
// (A-hi-only GEMM), then each runs the tail for 32 interleaved rows. Tail LDS:
// QX packed as bf16 pair in one word [d*65 + j] (bank = (d+j)%32, 2-way free)
// -> 33.5 KB total.
//   P' = exp(0.4A)*(-ln2/10); w = exp2(rcp(fma(P',q,-ln2/10))) = exp(-10/(1+u)).
struct MbloDir { const short* Ah;
                 const short* W1h; const short* W2h;
                 const float* mb; short* Hh; int fw; };

__global__ __launch_bounds__(512) void mblo_k(MbloDir p0, MbloDir p1)
{
    __shared__ char smraw[33536] __attribute__((aligned(16)));
    short* gAh  = (short*)smraw;            // 64*72 shorts each (GEMM phase)
    short* gB1h = gAh + 4608;
    short* gB2h = gAh + 9216;
    float* aP   = (float*)smraw;            // [i*66 + l] P' (tail overlay, 16.9 KB)
    unsigned int* aQX = (unsigned int*)(smraw + 16896); // [d*65 + j]: lo=Q bf16, hi=X bf16

    const float KLN = -0.06931471805599453f;   // -ln2/10

    MbloDir p = blockIdx.z ? p1 : p0;
    int tid = threadIdx.x;
    int w = tid >> 6, l = tid & 63;
    int m = l & 15, q = l >> 4;
    int rh = w >> 1;            // row strip 0..3
    int cb = (w & 1) * 2;       // col-frag base: 0 or 2
    int bn = blockIdx.x >> 1, ipar = blockIdx.x & 1;
    int row0 = bn * 64, d0 = blockIdx.y * 64;
    int srow = tid >> 3;        // staging row 0..63
    int skl  = (tid & 7) * 8;   // staging k offset

    f32x4 acc1[2], acc2[2];
    #pragma unroll
    for (int cf = 0; cf < 2; cf++) { acc1[cf] = (f32x4)(0.f); acc2[cf] = (f32x4)(0.f); }

    for (int kh = 0; kh < 4; kh++) {
        int kbase = kh * 64;
        size_t ga = (size_t)(row0 + srow) * 256 + kbase + skl;
        *(short8*)&gAh[srow * 72 + skl] = *(const short8*)(p.Ah + ga);
        size_t gb = (size_t)(d0 + srow) * 256 + kbase + skl;
        *(short8*)&gB1h[srow * 72 + skl] = *(const short8*)(p.W1h + gb);
        *(short8*)&gB2h[srow * 72 + skl] = *(const short8*)(p.W2h + gb);
        __syncthreads();
        #pragma unroll
        for (int ch = 0; ch < 2; ch++) {
            int k = ch * 32 + q * 8;
            short8 ah = *(const short8*)&gAh[(rh * 16 + m) * 72 + k];
            #pragma unroll
            for (int cf = 0; cf < 2; cf++) {
                int bofs = ((cb + cf) * 16 + m) * 72 + k;
                short8 b1 = *(const short8*)&gB1h[bofs];
                acc1[cf] = MFMA_B16(ah, b1, acc1[cf]);
                short8 b2 = *(const short8*)&gB2h[bofs];
                acc2[cf] = MFMA_B16(ah, b2, acc2[cf]);
            }
        }
        __syncthreads();   // also guards the union overwrite below
    }
    // epilogue: P' row-major f32; Q bf16 into low half of packed QX word
    short* sQX = (short*)aQX;
    #pragma unroll
    for (int cf = 0; cf < 2; cf++) {
        int col = (cb + cf) * 16 + m;        // d index
        float mbv = p.mb[d0 + col];
        #pragma unroll
        for (int r = 0; r < 4; r++) {
            int row = rh * 16 + q * 4 + r;   // j index
            aP[row * 66 + col] = __expf(0.4f * acc1[cf][r]) * KLN;
            sQX[col * 130 + 2 * row] = f2bs(__expf(0.4f * (acc2[cf][r] + mbv)));
        }
    }
    {   // X tile (bf16 hi plane, raw copy) into high halves
        size_t gx = (size_t)(row0 + srow) * 256 + d0 + skl;
        short8 xh = *(const short8*)(p.Ah + gx);
        #pragma unroll
        for (int t = 0; t < 8; t++)
            sQX[(skl + t) * 130 + 2 * srow + 1] = xh[t];
    }
    __syncthreads();
    // masked attention, exact bounds: wave w handles rows {ipar + 2*(w + 8t)}, t<4
    const unsigned int* lane_qx = &aQX[l * 65];
    #pragma unroll
    for (int t8 = 0; t8 < 4; t8++) {
        int i = ipar + 2 * (w + 8 * t8);
        float Pp = aP[i * 66 + l];
        int js = p.fw ? (i + 1) : 0;
        int je = p.fw ? 64 : i;
        float den0 = 0.f, den1 = 0.f, num0 = 0.f, num1 = 0.f;
        int j = js;
        for (; j + 4 <= je; j += 4) {
            unsigned int u0 = lane_qx[j];
            unsigned int u1 = lane_qx[j + 1];
            unsigned int u2 = lane_qx[j + 2];
            unsigned int u3 = lane_qx[j + 3];
            float q0 = bs2f((short)(u0 & 0xffff)), x0 = bs2f((short)(u0 >> 16));
            float q1 = bs2f((short)(u1 & 0xffff)), x1 = bs2f((short)(u1 >> 16));
            float q2 = bs2f((short)(u2 & 0xffff)), x2 = bs2f((short)(u2 >> 16));
            float q3 = bs2f((short)(u3 & 0xffff)), x3 = bs2f((short)(u3 >> 16));
            float w0 = EXP2F(__builtin_amdgcn_rcpf(fmaf(Pp, q0, KLN)));
            float w1 = EXP2F(__builtin_amdgcn_rcpf(fmaf(Pp, q1, KLN)));
            float w2 = EXP2F(__builtin_amdgcn_rcpf(fmaf(Pp, q2, KLN)));
            float w3 = EXP2F(__builtin_amdgcn_rcpf(fmaf(Pp, q3, KLN)));
            den0 += w0; num0 = fmaf(w0, x0, num0);
            den1 += w1; num1 = fmaf(w1, x1, num1);
            den0 += w2; num0 = fmaf(w2, x2, num0);
            den1 += w3; num1 = fmaf(w3, x3, num1);
        }
        for (; j < je; j++) {
            unsigned int u0 = lane_qx[j];
            float q0 = bs2f((short)(u0 & 0xffff)), x0 = bs2f((short)(u0 >> 16));
            float wgt = EXP2F(__builtin_amdgcn_rcpf(fmaf(Pp, q0, KLN)));
            den0 += wgt; num0 = fmaf(wgt, x0, num0);
        }
        float den = den0 + den1, num = num0 + num1;
        bool valid = p.fw ? (i < 63) : (i > 0);
        float out = valid ? (num * __builtin_amdgcn_rcpf(den)) : 0.f;
        p.Hh[(size_t)(row0 + i) * 256 + d0 + l] = f2bs(out);
    }
}

// ---------- fused s2t logits GEMM (single-plane W) + softmax pool ----------
struct PoolDir { const short* T1; const short* Wh; const float* bias;
                 const short* Hh; float* V; };

__global__ __launch_bounds__(256) void s2t_pool_k(PoolDir p0, PoolDir p1)
{
    __shared__ char smraw[37888] __attribute__((aligned(16)));
    short* gAh = (short*)smraw;             // 64*72
    short* gBh = gAh + 4608;
    float* aL = (float*)smraw;              // 64*68
    float* aH = aL + 4352;
    float* rm = aL + 8704;                  // 4*64
    float* rd = aL + 8960;
    float* rn = aL + 9216;

    PoolDir p = blockIdx.z ? p1 : p0;
    int tid = threadIdx.x;
    int w = tid >> 6, l = tid & 63;
    int m = l & 15, q = l >> 4;
    int sr = w * 16 + m;
    int row0 = blockIdx.x * 64, d0 = blockIdx.y * 64;

    f32x4 acc[4];
    #pragma unroll
    for (int cf = 0; cf < 4; cf++) acc[cf] = (f32x4)(0.f);

    for (int kh = 0; kh < 4; kh++) {
        int kbase = kh * 64;
        #pragma unroll
        for (int i = 0; i < 2; i++) {
            int kl = q * 8 + 32 * i;
            *(short8*)&gAh[sr * 72 + kl] =
                *(const short8*)(p.T1 + (size_t)(row0 + sr) * 256 + kbase + kl);
            *(short8*)&gBh[sr * 72 + kl] =
                *(const short8*)(p.Wh + (size_t)(d0 + sr) * 256 + kbase + kl);
        }
        __syncthreads();
        #pragma unroll
        for (int ch = 0; ch < 2; ch++) {
            int k = ch * 32 + q * 8;
            short8 ah = *(const short8*)&gAh[(w * 16 + m) * 72 + k];
            #pragma unroll
            for (int cf = 0; cf < 4; cf++) {
                short8 bh = *(const short8*)&gBh[(cf * 16 + m) * 72 + k];
                acc[cf] = MFMA_B16(ah, bh, acc[cf]);
            }
        }
        __syncthreads();
    }
    #pragma unroll
    for (int cf = 0; cf < 4; cf++) {
        int col = cf * 16 + m;
        float bv = p.bias[d0 + col];
        #pragma unroll
        for (int r = 0; r < 4; r++) {
            int row = w * 16 + q * 4 + r;
            aL[row * 68 + col] = acc[cf][r] + bv;
        }
    }
    #pragma unroll
    for (int it = 0; it < 2; it++) {
        int e = tid + it * 256;
        int j = e >> 3, d8 = (e & 7) * 8;
        short8 xh = *(const short8*)(p.Hh + (size_t)(row0 + j) * 256 + d0 + d8);
        #pragma unroll
        for (int t = 0; t < 8; t++)
            aH[j * 68 + d8 + t] = bs2f(xh[t]);
    }
    __syncthreads();
    int dl = tid & 63, rq = tid >> 6;
    float mx = -1e30f, den = 0.f, num = 0.f;
    #pragma unroll
    for (int rr = 0; rr < 16; rr++) {
        int r = rq * 16 + rr;
        float lv = aL[r * 68 + dl];
        float hv = aH[r * 68 + dl];
        if (lv > mx) {
            float sc = __expf(mx - lv);
            den *= sc; num *= sc; mx = lv;
        }
        float wgt = __expf(lv - mx);
        den += wgt; num += wgt * hv;
    }
    rm[rq * 64 + dl] = mx; rd[rq * 64 + dl] = den; rn[rq * 64 + dl] = num;
    __syncthreads();
    if (rq == 0) {
        float M = fmaxf(fmaxf(rm[dl], rm[64 + dl]), fmaxf(rm[128 + dl], rm[192 + dl]));
        float D = 0.f, Nn = 0.f;
        #pragma unroll
        for (int k = 0; k < 4; k++) {
            float sc = __expf(rm[k * 64 + dl] - M);
            D += rd[k * 64 + dl] * sc;
            Nn += rn[k * 64 + dl] * sc;
        }
        p.V[(size_t)blockIdx.x * 256 + d0 + dl] = Nn / D;
    }
}

// ---------- fused level-2 attention (row 0) + gate, with inline vW1/vW2 GEMV ----
// 512 threads, grid (4 b, 4 ychunk, 2 dir). fw blocks compute the only rows of
// v@mW1 / v@mW2 the attention ever reads (16 per b) as f32 register GEMVs over
// the RAW weights (more accurate than a bf16-split MFMA path), kk-range
// split across the two 256-thread halves with an LDS reduce. Then
// tanh-softmax attention + gate GEMM (8-way k-split).
struct Gate2Dir { const float* V; const float* W1; const float* W2; const float* mb;
                  const float* gW1; const float* gW2; const float* gb;
                  float* E0; int fw; };

__global__ __launch_bounds__(512) void attn2gate_k(Gate2Dir p0, Gate2Dir p1)
{
    Gate2Dir p = blockIdx.z ? p1 : p0;
    __shared__ __attribute__((aligned(16))) float sVT[4096];   // [kk*16+j] = v[b16+j][kk]
    __shared__ float sPart[16][256];
    __shared__ float so[256], sv[256], red[8][64];
    int tid = threadIdx.x;
    int b = blockIdx.x;
    int k = tid & 255, half = tid >> 8;

    if (p.fw) {
        #pragma unroll
        for (int it = 0; it < 8; it++) {
            int e = tid + it * 512;
            int kk = e >> 4, j = e & 15;
            sVT[e] = p.V[(size_t)(b * 16 + j) * 256 + kk];
        }
        __syncthreads();
        float acc[16];
        #pragma unroll
        for (int j = 0; j < 16; j++) acc[j] = 0.f;
        int kk0 = half * 128;
        #pragma unroll 4
        for (int kk = kk0; kk < kk0 + 128; kk++) {
            const float4* vr = (const float4*)&sVT[kk * 16];
            float4 va = vr[0], vb = vr[1], vc = vr[2], vd = vr[3];
            float w1 = p.W1[(size_t)kk * 256 + k];
            float w2 = p.W2[(size_t)kk * 256 + k];
            acc[0]  = fmaf(va.x, w1, acc[0]);
            acc[1]  = fmaf(va.y, w2, acc[1]);
            acc[2]  = fmaf(va.z, w2, acc[2]);
            acc[3]  = fmaf(va.w, w2, acc[3]);
            acc[4]  = fmaf(vb.x, w2, acc[4]);
            acc[5]  = fmaf(vb.y, w2, acc[5]);
            acc[6]  = fmaf(vb.z, w2, acc[6]);
            acc[7]  = fmaf(vb.w, w2, acc[7]);
            acc[8]  = fmaf(vc.x, w2, acc[8]);
            acc[9]  = fmaf(vc.y, w2, acc[9]);
            acc[10] = fmaf(vc.z, w2, acc[10]);
            acc[11] = fmaf(vc.w, w2, acc[11]);
            acc[12] = fmaf(vd.x, w2, acc[12]);
            acc[13] = fmaf(vd.y, w2, acc[13]);
            acc[14] = fmaf(vd.z, w2, acc[14]);
            acc[15] = fmaf(vd.w, w2, acc[15]);
        }
        if (half) {
            #pragma unroll
            for (int j = 0; j < 16; j++) sPart[j][k] = acc[j];
        }
        __syncthreads();
        if (!half) {
            #pragma unroll
            for (int j = 0; j < 16; j++) acc[j] += sPart[j][k];
            float base = acc[0] + p.mb[k];          // qv + mb (vW2 bias folded here)
            float den = 0.f, num = 0.f;
            #pragma unroll
            for (int j = 1; j < 16; j++) {
                float z = (base + acc[j]) * 0.2f;
                float e2 = __expf(2.f * z);
                float t = 1.f - 2.f / (e2 + 1.f);
                float wgt = __expf(5.f * t);
                den += wgt;
                num = fmaf(wgt, p.V[(size_t)(b * 16 + j) * 256 + k], num);
            }
            so[k] = num / den;
            sv[k] = p.V[(size_t)(b * 16) * 256 + k];
        }
    } else {
        if (!half) {
            so[k] = 0.f;
            sv[k] = p.V[(size_t)(b * 16) * 256 + k];
        }
    }
    __syncthreads();
    int c = tid & 63, ks = tid >> 6;
    int gc = blockIdx.y * 64 + c;
    float a2 = 0.f;
    int k0 = ks * 32;
    #pragma unroll 8
    for (int kkx = 0; kkx < 32; kkx++) {
        int kx = k0 + kkx;
        a2 += so[kx] * p.gW1[(size_t)kx * 256 + gc] + sv[kx] * p.gW2[(size_t)kx * 256 + gc];
    }
    red[ks][c] = a2;
    __syncthreads();
    if (ks == 0) {
        float a = red[0][c] + red[1][c] + red[2][c] + red[3][c]
                + red[4][c] + red[5][c] + red[6][c] + red[7][c] + p.gb[gc];
        float G = 1.f / (1.f + __expf(-a));
        p.E0[b * 256 + gc] = G * so[gc] + (1.f - G) * sv[gc];
    }
}

// ---------- fusion: grid (64 bt, 4 dchunk, 2 dir), split-K(4x192) x 64-col ----------
struct FuseDir { const short* INh; const short* Hh;
                 const float* E0; const float* fW1; const float* fb1;
                 const float* fW2; const float* fb2; };

__global__ __launch_bounds__(256) void fusion_k(FuseDir p0, FuseDir p1, float* __restrict__ out)
{
    FuseDir p = blockIdx.z ? p1 : p0;
    __shared__ float cat[768];
    __shared__ float red1[4][64], red2[4][64];
    int bt = blockIdx.x, b = bt >> 4, t = bt & 15;
    int c = threadIdx.x & 63, ks = threadIdx.x >> 6;
    int gc = blockIdx.y * 64 + c;
    size_t xrow = ((size_t)b * 1024 + t) * 256;   // (b, n=0, r=t)
    cat[threadIdx.x]       = bs2f(p.INh[xrow + threadIdx.x]);
    cat[256 + threadIdx.x] = bs2f(p.Hh[xrow + threadIdx.x]);
    cat[512 + threadIdx.x] = p.E0[b * 256 + threadIdx.x];
    __syncthreads();
    float a1 = 0.f, a2 = 0.f;
    int k0 = ks * 192;
    #pragma unroll 8
    for (int kk = 0; kk < 192; kk++) {
        int k = k0 + kk;
        float cv = cat[k];
        a1 += cv * p.fW1[(size_t)k * 256 + gc];
        a2 += cv * p.fW2[(size_t)k * 256 + gc];
    }
    red1[ks][c] = a1; red2[ks][c] = a2;
    __syncthreads();
    if (ks == 0) {
        float s1 = red1[0][c] + red1[1][c] + red1[2][c] + red1[3][c] + p.fb1[gc];
        float s2 = red2[0][c] + red2[1][c] + red2[2][c] + red2[3][c] + p.fb2[gc];
        float fus = fmaxf(s1, 0.f);
        float Gf = 1.f / (1.f + __expf(-s2));
        float u = Gf * fus + (1.f - Gf) * cat[gc];
        out[((size_t)(b * 16 + t)) * 512 + (size_t)blockIdx.z * 256 + gc] = u;
    }
}

extern "C" void kernel_launch(void* const* d_in, const int* in_sizes, int n_in,
                              void* d_out, int out_size, void* d_ws, size_t ws_size,
                              hipStream_t stream)
{
    const float* x = (const float*)d_in[0];
    char* base = (char*)d_ws;
    auto alloc = [&](size_t bytes){ void* r = base; base += (bytes + 255) & ~255ULL; return r; };
    short* inH = (short*)alloc(2 * 1048576 * 2);
    short* hH  = (short*)alloc(2 * 1048576 * 2);
    short* t1  = (short*)alloc(2 * 1048576 * 2);
    short* wtH = (short*)alloc(10 * 65536 * 2);
    short* wtL = (short*)alloc(10 * 65536 * 2);
    short* xh  = (short*)alloc(1048576 * 2);
    short* xl  = (short*)alloc(1048576 * 2);
    float* v   = (float*)alloc(2 * 16384 * 4);
    float* E0  = (float*)alloc(2 * 1024 * 4);

    SrcPack sp;
    const int src_idx[5] = {0, 2, 3, 5, 7};  // fcW, mW1, mW2, s2tW1, s2tW
    for (int p = 0; p < 2; p++)
        for (int i = 0; i < 5; i++)
            sp.s[p * 5 + i] = (const float*)d_in[1 + p * 16 + src_idx[i]];
    prep_k<<<dim3(16, 14), 256, 0, stream>>>(sp, x, wtH, wtL, xh, xl);

    GDir fc[2], s2t1[2];
    MbloDir mbd[2];
    PoolDir pld[2];
    Gate2Dir gtd[2];
    FuseDir fsd[2];
    for (int p = 0; p < 2; p++) {
        int bi = 1 + p * 16;
        const float* fcb   = (const float*)d_in[bi + 1];
        const float* mb    = (const float*)d_in[bi + 4];
        const float* s2tb1 = (const float*)d_in[bi + 6];
        const float* s2tb  = (const float*)d_in[bi + 8];
        size_t po = (size_t)p * 1048576;
        const short* W0h = wtH + (size_t)(p * 5 + 0) * 65536, *W0l = wtL + (size_t)(p * 5 + 0) * 65536;
        const short* W1h = wtH + (size_t)(p * 5 + 1) * 65536;
        const short* W2h = wtH + (size_t)(p * 5 + 2) * 65536;
        const short* W3h = wtH + (size_t)(p * 5 + 3) * 65536;
        const short* W4h = wtH + (size_t)(p * 5 + 4) * 65536;

        fc[p]   = { xh, xl, W0h, W0l, fcb, inH + po };
        mbd[p]  = { inH + po, W1h, W2h, mb, hH + po, (p == 0) };
        s2t1[p] = { hH + po, nullptr, W3h, nullptr, s2tb1, t1 + po };
        pld[p]  = { t1 + po, W4h, s2tb, hH + po, v + p * 16384 };
        gtd[p]  = { v + p * 16384,
                    (const float*)d_in[bi + 2], (const float*)d_in[bi + 3], mb,
                    (const float*)d_in[bi + 9], (const float*)d_in[bi + 10],
                    (const float*)d_in[bi + 11], E0 + p * 1024, (p == 0) };
        fsd[p]  = { inH + po, hH + po, E0 + p * 1024,
                    (const float*)d_in[bi + 12], (const float*)d_in[bi + 13],
                    (const float*)d_in[bi + 14], (const float*)d_in[bi + 15] };
    }

    gemm_k<2, 1, 1, 0><<<dim3(64, 4, 2), 256, 0, stream>>>(fc[0], fc[1]);
    mblo_k<<<dim3(128, 4, 2), 512, 0, stream>>>(mbd[0], mbd[1]);
    gemm_k<0, 1, 1, 1><<<dim3(64, 4, 2), 256, 0, stream>>>(s2t1[0], s2t1[1]);
    s2t_pool_k<<<dim3(64, 4, 2), 256, 0, stream>>>(pld[0], pld[1]);
    attn2gate_k<<<dim3(4, 4, 2), 512, 0, stream>>>(gtd[0], gtd[1]);
    fusion_k<<<dim3(64, 4, 2), 256, 0, stream>>>(fsd[0], fsd[1], (float*)d_out);
}

// Round 4
// 209.822 us; speedup vs baseline: 1.0503x; 1.0076x over previous
//
#include <hip/hip_runtime.h>
#include <hip/hip_cooperative_groups.h>
#include <hip/hip_bf16.h>

typedef __hip_bfloat16 BF16;
typedef __attribute__((ext_vector_type(8))) short short8;
typedef __attribute__((ext_vector_type(4))) short short4v;
typedef __attribute__((ext_vector_type(4))) float f32x4;

#define MFMA_B16(a,b,c) __builtin_amdgcn_mfma_f32_16x16x32_bf16((a),(b),(c),0,0,0)

#if __has_builtin(__builtin_amdgcn_exp2f)
#define EXP2F(x) __builtin_amdgcn_exp2f(x)
#else
#define EXP2F(x) __expf(0.6931471805599453f * (x))
#endif

__device__ __forceinline__ short f2bs(float f){ BF16 h = __float2bfloat16(f); return *(short*)&h; }
__device__ __forceinline__ float bs2f(short s){ BF16 h = *(BF16*)&s; return __bfloat162float(h); }

struct SrcPack { const float* s[10]; };
struct GDir { const void* A0; const void* Al; const short* Wh; const short* Wl;
              const float* bias; void* O0; };
struct MbloDir { const short* Ah; const short* W1h; const short* W2h;
                 const float* mb; short* Hh; int fw; };
struct PoolDir { const short* T1; const short* Wh; const float* bias;
                 const short* Hh; float* V; };
struct Gate2Dir { const float* V; const float* W1; const float* W2; const float* mb;
                  const float* gW1; const float* gW2; const float* gb;
                  float* E0; int fw; };
struct FuseDir { const short* INh; const short* Hh;
                 const float* E0; const float* fW1; const float* fb1;
                 const float* fW2; const float* fb2; };

// ============================================================================
// ===================  FALLBACK (proven 7-kernel path)  ======================
// ============================================================================

__global__ __launch_bounds__(256) void prep_k(SrcPack p, const float* __restrict__ X,
                                              short* __restrict__ Oh,
                                              short* __restrict__ Ol,
                                              short* __restrict__ Xh,
                                              short* __restrict__ Xl)
{
    if (blockIdx.y >= 10) {
        int u = (blockIdx.y - 10) * 16 + blockIdx.x;
        size_t base = (size_t)u * 16384;
        #pragma unroll
        for (int i = 0; i < 16; i++) {
            size_t idx = base + (size_t)i * 1024 + threadIdx.x * 4;
            float4 f = *(const float4*)(X + idx);
            short4v vh, vl;
            float t0[4] = {f.x, f.y, f.z, f.w};
            #pragma unroll
            for (int j = 0; j < 4; j++) {
                vh[j] = f2bs(t0[j]);
                vl[j] = f2bs(t0[j] - bs2f(vh[j]));
            }
            *(short4v*)(Xh + idx) = vh;
            *(short4v*)(Xl + idx) = vl;
        }
        return;
    }
    __shared__ float s[64][65];
    const float* W = p.s[blockIdx.y];
    short* oh = Oh + (size_t)blockIdx.y * 65536;
    short* ol = Ol + (size_t)blockIdx.y * 65536;
    int tr = (blockIdx.x >> 2) * 64, tc = (blockIdx.x & 3) * 64;
    #pragma unroll
    for (int i = 0; i < 16; i++) {
        int e = threadIdx.x + i * 256;
        int r = e >> 6, c = e & 63;
        s[c][r] = W[(size_t)(tr + r) * 256 + tc + c];
    }
    __syncthreads();
    #pragma unroll
    for (int i = 0; i < 16; i++) {
        int e = threadIdx.x + i * 256;
        int c2 = e >> 6, r2 = e & 63;
        float v = s[c2][r2];
        short hi = f2bs(v);
        short lo = f2bs(v - bs2f(hi));
        size_t oi = (size_t)(tc + c2) * 256 + tr + r2;
        oh[oi] = hi;
        ol[oi] = lo;
    }
}

template<int AM, int OM, int RELU, int BS>
__device__ __forceinline__ void gemm_body(const void* __restrict__ A0,
    const void* __restrict__ Alo,
    const short* __restrict__ Wh, const short* __restrict__ Wl,
    const float* __restrict__ bias, void* __restrict__ O0,
    int row0, int col0)
{
    constexpr int LDK = 72;
    __shared__ short sAh[64 * LDK];
    __shared__ short sAl[(AM == 0) ? 8 : 64 * LDK];
    __shared__ short sBh[64 * LDK];
    __shared__ short sBl[BS ? 8 : 64 * LDK];
    int tid = threadIdx.x;
    int w = tid >> 6, l = tid & 63;
    int m = l & 15, q = l >> 4;
    int sr = w * 16 + m;

    f32x4 acc[4];
    #pragma unroll
    for (int cf = 0; cf < 4; cf++) acc[cf] = (f32x4)(0.f);

    for (int kh = 0; kh < 4; kh++) {
        int kbase = kh * 64;
        #pragma unroll
        for (int i = 0; i < 2; i++) {
            int kl = q * 8 + 32 * i;
            size_t gofs = (size_t)(row0 + sr) * 256 + kbase + kl;
            if (AM == 2) {
                *(short8*)&sAh[sr * LDK + kl] = *(const short8*)((const short*)A0 + gofs);
                *(short8*)&sAl[sr * LDK + kl] = *(const short8*)((const short*)Alo + gofs);
            } else {
                *(short8*)&sAh[sr * LDK + kl] = *(const short8*)((const short*)A0 + gofs);
            }
            size_t gofsB = (size_t)(col0 + sr) * 256 + kbase + kl;
            *(short8*)&sBh[sr * LDK + kl] = *(const short8*)(Wh + gofsB);
            if (!BS)
                *(short8*)&sBl[sr * LDK + kl] = *(const short8*)(Wl + gofsB);
        }
        __syncthreads();
        #pragma unroll
        for (int ch = 0; ch < 2; ch++) {
            int k = ch * 32 + q * 8;
            short8 ah = *(const short8*)&sAh[(w * 16 + m) * LDK + k];
            short8 al = (AM != 0) ? *(const short8*)&sAl[(w * 16 + m) * LDK + k] : ah;
            #pragma unroll
            for (int cf = 0; cf < 4; cf++) {
                short8 bh = *(const short8*)&sBh[(cf * 16 + m) * LDK + k];
                acc[cf] = MFMA_B16(ah, bh, acc[cf]);
                if (!BS) {
                    short8 bl = *(const short8*)&sBl[(cf * 16 + m) * LDK + k];
                    acc[cf] = MFMA_B16(ah, bl, acc[cf]);
                }
                if (AM != 0)
                    acc[cf] = MFMA_B16(al, bh, acc[cf]);
            }
        }
        __syncthreads();
    }
    #pragma unroll
    for (int cf = 0; cf < 4; cf++) {
        int col = col0 + cf * 16 + m;
        float bv = bias ? bias[col] : 0.f;
        #pragma unroll
        for (int r = 0; r < 4; r++) {
            int row = row0 + w * 16 + q * 4 + r;
            float v = acc[cf][r] + bv;
            if (RELU) v = fmaxf(v, 0.f);
            size_t oi = (size_t)row * 256 + col;
            if (OM == 0) {
                ((float*)O0)[oi] = v;
            } else {
                ((short*)O0)[oi] = f2bs(v);
            }
        }
    }
}

template<int AM, int OM, int RELU, int BS>
__global__ __launch_bounds__(256) void gemm_k(GDir p0, GDir p1)
{
    GDir p = blockIdx.z ? p1 : p0;
    gemm_body<AM, OM, RELU, BS>(p.A0, p.Al, p.Wh, p.Wl, p.bias, p.O0,
                                blockIdx.x * 64, blockIdx.y * 64);
}

__global__ __launch_bounds__(512) void mblo_k(MbloDir p0, MbloDir p1)
{
    __shared__ char smraw[33536] __attribute__((aligned(16)));
    short* gAh  = (short*)smraw;
    short* gB1h = gAh + 4608;
    short* gB2h = gAh + 9216;
    float* aP   = (float*)smraw;
    unsigned int* aQX = (unsigned int*)(smraw + 16896);

    const float KLN = -0.06931471805599453f;

    MbloDir p = blockIdx.z ? p1 : p0;
    int tid = threadIdx.x;
    int w = tid >> 6, l = tid & 63;
    int m = l & 15, q = l >> 4;
    int rh = w >> 1;
    int cb = (w & 1) * 2;
    int bn = blockIdx.x >> 1, ipar = blockIdx.x & 1;
    int row0 = bn * 64, d0 = blockIdx.y * 64;
    int srow = tid >> 3;
    int skl  = (tid & 7) * 8;

    f32x4 acc1[2], acc2[2];
    #pragma unroll
    for (int cf = 0; cf < 2; cf++) { acc1[cf] = (f32x4)(0.f); acc2[cf] = (f32x4)(0.f); }

    for (int kh = 0; kh < 4; kh++) {
        int kbase = kh * 64;
        size_t ga = (size_t)(row0 + srow) * 256 + kbase + skl;
        *(short8*)&gAh[srow * 72 + skl] = *(const short8*)(p.Ah + ga);
        size_t gb = (size_t)(d0 + srow) * 256 + kbase + skl;
        *(short8*)&gB1h[srow * 72 + skl] = *(const short8*)(p.W1h + gb);
        *(short8*)&gB2h[srow * 72 + skl] = *(const short8*)(p.W2h + gb);
        __syncthreads();
        #pragma unroll
        for (int ch = 0; ch < 2; ch++) {
            int k = ch * 32 + q * 8;
            short8 ah = *(const short8*)&gAh[(rh * 16 + m) * 72 + k];
            #pragma unroll
            for (int cf = 0; cf < 2; cf++) {
                int bofs = ((cb + cf) * 16 + m) * 72 + k;
                short8 b1 = *(const short8*)&gB1h[bofs];
                acc1[cf] = MFMA_B16(ah, b1, acc1[cf]);
                short8 b2 = *(const short8*)&gB2h[bofs];
                acc2[cf] = MFMA_B16(ah, b2, acc2[cf]);
            }
        }
        __syncthreads();
    }
    short* sQX = (short*)aQX;
    #pragma unroll
    for (int cf = 0; cf < 2; cf++) {
        int col = (cb + cf) * 16 + m;
        float mbv = p.mb[d0 + col];
        #pragma unroll
        for (int r = 0; r < 4; r++) {
            int row = rh * 16 + q * 4 + r;
            aP[row * 66 + col] = __expf(0.4f * acc1[cf][r]) * KLN;
            sQX[col * 130 + 2 * row] = f2bs(__expf(0.4f * (acc2[cf][r] + mbv)));
        }
    }
    {
        size_t gx = (size_t)(row0 + srow) * 256 + d0 + skl;
        short8 xh = *(const short8*)(p.Ah + gx);
        #pragma unroll
        for (int t = 0; t < 8; t++)
            sQX[(skl + t) * 130 + 2 * srow + 1] = xh[t];
    }
    __syncthreads();
    const unsigned int* lane_qx = &aQX[l * 65];
    #pragma unroll
    for (int t8 = 0; t8 < 4; t8++) {
        int i = ipar + 2 * (w + 8 * t8);
        float Pp = aP[i * 66 + l];
        int js = p.fw ? (i + 1) : 0;
        int je = p.fw ? 64 : i;
        float den0 = 0.f, den1 = 0.f, num0 = 0.f, num1 = 0.f;
        int j = js;
        for (; j + 4 <= je; j += 4) {
            unsigned int u0 = lane_qx[j];
            unsigned int u1 = lane_qx[j + 1];
            unsigned int u2 = lane_qx[j + 2];
            unsigned int u3 = lane_qx[j + 3];
            float q0 = bs2f((short)(u0 & 0xffff)), x0 = bs2f((short)(u0 >> 16));
            float q1 = bs2f((short)(u1 & 0xffff)), x1 = bs2f((short)(u1 >> 16));
            float q2 = bs2f((short)(u2 & 0xffff)), x2 = bs2f((short)(u2 >> 16));
            float q3 = bs2f((short)(u3 & 0xffff)), x3 = bs2f((short)(u3 >> 16));
            float w0 = EXP2F(__builtin_amdgcn_rcpf(fmaf(Pp, q0, KLN)));
            float w1 = EXP2F(__builtin_amdgcn_rcpf(fmaf(Pp, q1, KLN)));
            float w2 = EXP2F(__builtin_amdgcn_rcpf(fmaf(Pp, q2, KLN)));
            float w3 = EXP2F(__builtin_amdgcn_rcpf(fmaf(Pp, q3, KLN)));
            den0 += w0; num0 = fmaf(w0, x0, num0);
            den1 += w1; num1 = fmaf(w1, x1, num1);
            den0 += w2; num0 = fmaf(w2, x2, num0);
            den1 += w3; num1 = fmaf(w3, x3, num1);
        }
        for (; j < je; j++) {
            unsigned int u0 = lane_qx[j];
            float q0 = bs2f((short)(u0 & 0xffff)), x0 = bs2f((short)(u0 >> 16));
            float wgt = EXP2F(__builtin_amdgcn_rcpf(fmaf(Pp, q0, KLN)));
            den0 += wgt; num0 = fmaf(wgt, x0, num0);
        }
        float den = den0 + den1, num = num0 + num1;
        bool valid = p.fw ? (i < 63) : (i > 0);
        float out = valid ? (num * __builtin_amdgcn_rcpf(den)) : 0.f;
        p.Hh[(size_t)(row0 + i) * 256 + d0 + l] = f2bs(out);
    }
}

__global__ __launch_bounds__(256) void s2t_pool_k(PoolDir p0, PoolDir p1)
{
    __shared__ char smraw[37888] __attribute__((aligned(16)));
    short* gAh = (short*)smraw;
    short* gBh = gAh + 4608;
    float* aL = (float*)smraw;
    float* aH = aL + 4352;
    float* rm = aL + 8704;
    float* rd = aL + 8960;
    float* rn = aL + 9216;

    PoolDir p = blockIdx.z ? p1 : p0;
    int tid = threadIdx.x;
    int w = tid >> 6, l = tid & 63;
    int m = l & 15, q = l >> 4;
    int sr = w * 16 + m;
    int row0 = blockIdx.x * 64, d0 = blockIdx.y * 64;

    f32x4 acc[4];
    #pragma unroll
    for (int cf = 0; cf < 4; cf++) acc[cf] = (f32x4)(0.f);

    for (int kh = 0; kh < 4; kh++) {
        int kbase = kh * 64;
        #pragma unroll
        for (int i = 0; i < 2; i++) {
            int kl = q * 8 + 32 * i;
            *(short8*)&gAh[sr * 72 + kl] =
                *(const short8*)(p.T1 + (size_t)(row0 + sr) * 256 + kbase + kl);
            *(short8*)&gBh[sr * 72 + kl] =
                *(const short8*)(p.Wh + (size_t)(d0 + sr) * 256 + kbase + kl);
        }
        __syncthreads();
        #pragma unroll
        for (int ch = 0; ch < 2; ch++) {
            int k = ch * 32 + q * 8;
            short8 ah = *(const short8*)&gAh[(w * 16 + m) * 72 + k];
            #pragma unroll
            for (int cf = 0; cf < 4; cf++) {
                short8 bh = *(const short8*)&gBh[(cf * 16 + m) * 72 + k];
                acc[cf] = MFMA_B16(ah, bh, acc[cf]);
            }
        }
        __syncthreads();
    }
    #pragma unroll
    for (int cf = 0; cf < 4; cf++) {
        int col = cf * 16 + m;
        float bv = p.bias[d0 + col];
        #pragma unroll
        for (int r = 0; r < 4; r++) {
            int row = w * 16 + q * 4 + r;
            aL[row * 68 + col] = acc[cf][r] + bv;
        }
    }
    #pragma unroll
    for (int it = 0; it < 2; it++) {
        int e = tid + it * 256;
        int j = e >> 3, d8 = (e & 7) * 8;
        short8 xh = *(const short8*)(p.Hh + (size_t)(row0 + j) * 256 + d0 + d8);
        #pragma unroll
        for (int t = 0; t < 8; t++)
            aH[j * 68 + d8 + t] = bs2f(xh[t]);
    }
    __syncthreads();
    int dl = tid & 63, rq = tid >> 6;
    float mx = -1e30f, den = 0.f, num = 0.f;
    #pragma unroll
    for (int rr = 0; rr < 16; rr++) {
        int r = rq * 16 + rr;
        float lv = aL[r * 68 + dl];
        float hv = aH[r * 68 + dl];
        if (lv > mx) {
            float sc = __expf(mx - lv);
            den *= sc; num *= sc; mx = lv;
        }
        float wgt = __expf(lv - mx);
        den += wgt; num += wgt * hv;
    }
    rm[rq * 64 + dl] = mx; rd[rq * 64 + dl] = den; rn[rq * 64 + dl] = num;
    __syncthreads();
    if (rq == 0) {
        float M = fmaxf(fmaxf(rm[dl], rm[64 + dl]), fmaxf(rm[128 + dl], rm[192 + dl]));
        float D = 0.f, Nn = 0.f;
        #pragma unroll
        for (int k = 0; k < 4; k++) {
            float sc = __expf(rm[k * 64 + dl] - M);
            D += rd[k * 64 + dl] * sc;
            Nn += rn[k * 64 + dl] * sc;
        }
        p.V[(size_t)blockIdx.x * 256 + d0 + dl] = Nn / D;
    }
}

__global__ __launch_bounds__(512) void attn2gate_k(Gate2Dir p0, Gate2Dir p1)
{
    Gate2Dir p = blockIdx.z ? p1 : p0;
    __shared__ __attribute__((aligned(16))) float sVT[4096];
    __shared__ float sPart[16][256];
    __shared__ float so[256], sv[256], red[8][64];
    int tid = threadIdx.x;
    int b = blockIdx.x;
    int k = tid & 255, half = tid >> 8;

    if (p.fw) {
        #pragma unroll
        for (int it = 0; it < 8; it++) {
            int e = tid + it * 512;
            int kk = e >> 4, j = e & 15;
            sVT[e] = p.V[(size_t)(b * 16 + j) * 256 + kk];
        }
        __syncthreads();
        float acc[16];
        #pragma unroll
        for (int j = 0; j < 16; j++) acc[j] = 0.f;
        int kk0 = half * 128;
        #pragma unroll 4
        for (int kk = kk0; kk < kk0 + 128; kk++) {
            const float4* vr = (const float4*)&sVT[kk * 16];
            float4 va = vr[0], vb = vr[1], vc = vr[2], vd = vr[3];
            float w1 = p.W1[(size_t)kk * 256 + k];
            float w2 = p.W2[(size_t)kk * 256 + k];
            acc[0]  = fmaf(va.x, w1, acc[0]);
            acc[1]  = fmaf(va.y, w2, acc[1]);
            acc[2]  = fmaf(va.z, w2, acc[2]);
            acc[3]  = fmaf(va.w, w2, acc[3]);
            acc[4]  = fmaf(vb.x, w2, acc[4]);
            acc[5]  = fmaf(vb.y, w2, acc[5]);
            acc[6]  = fmaf(vb.z, w2, acc[6]);
            acc[7]  = fmaf(vb.w, w2, acc[7]);
            acc[8]  = fmaf(vc.x, w2, acc[8]);
            acc[9]  = fmaf(vc.y, w2, acc[9]);
            acc[10] = fmaf(vc.z, w2, acc[10]);
            acc[11] = fmaf(vc.w, w2, acc[11]);
            acc[12] = fmaf(vd.x, w2, acc[12]);
            acc[13] = fmaf(vd.y, w2, acc[13]);
            acc[14] = fmaf(vd.z, w2, acc[14]);
            acc[15] = fmaf(vd.w, w2, acc[15]);
        }
        if (half) {
            #pragma unroll
            for (int j = 0; j < 16; j++) sPart[j][k] = acc[j];
        }
        __syncthreads();
        if (!half) {
            #pragma unroll
            for (int j = 0; j < 16; j++) acc[j] += sPart[j][k];
            float base = acc[0] + p.mb[k];
            float den = 0.f, num = 0.f;
            #pragma unroll
            for (int j = 1; j < 16; j++) {
                float z = (base + acc[j]) * 0.2f;
                float e2 = __expf(2.f * z);
                float t = 1.f - 2.f / (e2 + 1.f);
                float wgt = __expf(5.f * t);
                den += wgt;
                num = fmaf(wgt, p.V[(size_t)(b * 16 + j) * 256 + k], num);
            }
            so[k] = num / den;
            sv[k] = p.V[(size_t)(b * 16) * 256 + k];
        }
    } else {
        if (!half) {
            so[k] = 0.f;
            sv[k] = p.V[(size_t)(b * 16) * 256 + k];
        }
    }
    __syncthreads();
    int c = tid & 63, ks = tid >> 6;
    int gc = blockIdx.y * 64 + c;
    float a2 = 0.f;
    int k0 = ks * 32;
    #pragma unroll 8
    for (int kkx = 0; kkx < 32; kkx++) {
        int kx = k0 + kkx;
        a2 += so[kx] * p.gW1[(size_t)kx * 256 + gc] + sv[kx] * p.gW2[(size_t)kx * 256 + gc];
    }
    red[ks][c] = a2;
    __syncthreads();
    if (ks == 0) {
        float a = red[0][c] + red[1][c] + red[2][c] + red[3][c]
                + red[4][c] + red[5][c] + red[6][c] + red[7][c] + p.gb[gc];
        float G = 1.f / (1.f + __expf(-a));
        p.E0[b * 256 + gc] = G * so[gc] + (1.f - G) * sv[gc];
    }
}

__global__ __launch_bounds__(256) void fusion_k(FuseDir p0, FuseDir p1, float* __restrict__ out)
{
    FuseDir p = blockIdx.z ? p1 : p0;
    __shared__ float cat[768];
    __shared__ float red1[4][64], red2[4][64];
    int bt = blockIdx.x, b = bt >> 4, t = bt & 15;
    int c = threadIdx.x & 63, ks = threadIdx.x >> 6;
    int gc = blockIdx.y * 64 + c;
    size_t xrow = ((size_t)b * 1024 + t) * 256;
    cat[threadIdx.x]       = bs2f(p.INh[xrow + threadIdx.x]);
    cat[256 + threadIdx.x] = bs2f(p.Hh[xrow + threadIdx.x]);
    cat[512 + threadIdx.x] = p.E0[b * 256 + threadIdx.x];
    __syncthreads();
    float a1 = 0.f, a2 = 0.f;
    int k0 = ks * 192;
    #pragma unroll 8
    for (int kk = 0; kk < 192; kk++) {
        int k = k0 + kk;
        float cv = cat[k];
        a1 += cv * p.fW1[(size_t)k * 256 + gc];
        a2 += cv * p.fW2[(size_t)k * 256 + gc];
    }
    red1[ks][c] = a1; red2[ks][c] = a2;
    __syncthreads();
    if (ks == 0) {
        float s1 = red1[0][c] + red1[1][c] + red1[2][c] + red1[3][c] + p.fb1[gc];
        float s2 = red2[0][c] + red2[1][c] + red2[2][c] + red2[3][c] + p.fb2[gc];
        float fus = fmaxf(s1, 0.f);
        float Gf = 1.f / (1.f + __expf(-s2));
        float u = Gf * fus + (1.f - Gf) * cat[gc];
        out[((size_t)(b * 16 + t)) * 512 + (size_t)blockIdx.z * 256 + gc] = u;
    }
}

// ============================================================================
// =====================  COOPERATIVE MEGA-KERNEL  ============================
// One dispatch, 7 phases separated by grid.sync(). All phases job-loop over a
// runtime grid (sized by occupancy query), so any co-residency level is valid.
// Phase bodies are 512-thread ports of the proven kernels above.
// ============================================================================

struct MegaP {
    SrcPack sp; const float* X;
    short *wtH, *wtL, *xh, *xl;
    GDir fc[2], s2t1[2];
    MbloDir mbd[2];
    PoolDir pld[2];
    Gate2Dir gtd[2];
    FuseDir fsd[2];
    float* out;
};

// 512-thread 64x64 GEMM: 8 waves = 4 row-strips x 2 col-halves; acc[2] per wave.
// Same per-output MFMA order as gemm_body (bit-identical results).
template<int AM, int OM, int RELU, int BS>
__device__ __forceinline__ void gemm512(const void* __restrict__ A0,
    const void* __restrict__ Alo,
    const short* __restrict__ Wh, const short* __restrict__ Wl,
    const float* __restrict__ bias, void* __restrict__ O0,
    int row0, int col0, char* SM)
{
    short* sAh = (short*)SM;              // 9216 B
    short* sAl = (short*)(SM + 9216);     // AM==2 only
    short* sBh = (short*)(SM + 18432);
    short* sBl = (short*)(SM + 27648);    // !BS only
    int tid = threadIdx.x;
    int w = tid >> 6, l = tid & 63, m = l & 15, q = l >> 4;
    int strip = w >> 1, chalf = w & 1;
    int srow = tid >> 3, skl = (tid & 7) * 8;
    f32x4 acc[2];
    acc[0] = (f32x4)(0.f); acc[1] = (f32x4)(0.f);
    for (int kh = 0; kh < 4; kh++) {
        int kb = kh * 64;
        size_t ga = (size_t)(row0 + srow) * 256 + kb + skl;
        *(short8*)&sAh[srow * 72 + skl] = *(const short8*)((const short*)A0 + ga);
        if (AM == 2)
            *(short8*)&sAl[srow * 72 + skl] = *(const short8*)((const short*)Alo + ga);
        size_t gb = (size_t)(col0 + srow) * 256 + kb + skl;
        *(short8*)&sBh[srow * 72 + skl] = *(const short8*)(Wh + gb);
        if (!BS)
            *(short8*)&sBl[srow * 72 + skl] = *(const short8*)(Wl + gb);
        __syncthreads();
        #pragma unroll
        for (int ch = 0; ch < 2; ch++) {
            int k = ch * 32 + q * 8;
            short8 ah = *(const short8*)&sAh[(strip * 16 + m) * 72 + k];
            short8 al = (AM == 2) ? *(const short8*)&sAl[(strip * 16 + m) * 72 + k] : ah;
            #pragma unroll
            for (int cf = 0; cf < 2; cf++) {
                int bofs = ((chalf * 2 + cf) * 16 + m) * 72 + k;
                short8 bh = *(const short8*)&sBh[bofs];
                acc[cf] = MFMA_B16(ah, bh, acc[cf]);
                if (!BS) {
                    short8 bl = *(const short8*)&sBl[bofs];
                    acc[cf] = MFMA_B16(ah, bl, acc[cf]);
                }
                if (AM == 2)
                    acc[cf] = MFMA_B16(al, bh, acc[cf]);
            }
        }
        __syncthreads();
    }
    #pragma unroll
    for (int cf = 0; cf < 2; cf++) {
        int col = col0 + (chalf * 2 + cf) * 16 + m;
        float bv = bias ? bias[col] : 0.f;
        #pragma unroll
        for (int r = 0; r < 4; r++) {
            int row = row0 + strip * 16 + q * 4 + r;
            float v = acc[cf][r] + bv;
            if (RELU) v = fmaxf(v, 0.f);
            size_t oi = (size_t)row * 256 + col;
            if (OM == 0) ((float*)O0)[oi] = v;
            else ((short*)O0)[oi] = f2bs(v);
        }
    }
}

__global__ __launch_bounds__(512) void mega_k(MegaP mp)
{
    __shared__ char SM[40960] __attribute__((aligned(16)));
    cooperative_groups::grid_group gg = cooperative_groups::this_grid();
    const int tid = threadIdx.x;
    const int bid = blockIdx.x, nb = gridDim.x;
    const float KLN = -0.06931471805599453f;

    // ---------------- phase P: weight transpose/split + x split ----------------
    for (int job = bid; job < 224; job += nb) {
        if (job < 160) {
            int mat = job >> 4, tile = job & 15;
            float (*s)[65] = (float(*)[65])SM;
            const float* W = mp.sp.s[mat];
            short* oh = mp.wtH + (size_t)mat * 65536;
            short* ol = mp.wtL + (size_t)mat * 65536;
            int tr = (tile >> 2) * 64, tc = (tile & 3) * 64;
            #pragma unroll
            for (int i = 0; i < 8; i++) {
                int e = tid + i * 512;
                int r = e >> 6, c = e & 63;
                s[c][r] = W[(size_t)(tr + r) * 256 + tc + c];
            }
            __syncthreads();
            #pragma unroll
            for (int i = 0; i < 8; i++) {
                int e = tid + i * 512;
                int c2 = e >> 6, r2 = e & 63;
                float v = s[c2][r2];
                short hi = f2bs(v);
                short lo = f2bs(v - bs2f(hi));
                size_t oi = (size_t)(tc + c2) * 256 + tr + r2;
                oh[oi] = hi;
                ol[oi] = lo;
            }
            __syncthreads();
        } else {
            int u = job - 160;
            size_t base = (size_t)u * 16384;
            #pragma unroll
            for (int i = 0; i < 8; i++) {
                size_t idx = base + (size_t)i * 2048 + tid * 4;
                float4 f = *(const float4*)(mp.X + idx);
                short4v vh, vl;
                float t0[4] = {f.x, f.y, f.z, f.w};
                #pragma unroll
                for (int j = 0; j < 4; j++) {
                    vh[j] = f2bs(t0[j]);
                    vl[j] = f2bs(t0[j] - bs2f(vh[j]));
                }
                *(short4v*)(mp.xh + idx) = vh;
                *(short4v*)(mp.xl + idx) = vl;
            }
        }
    }
    gg.sync();

    // ---------------- phase FC: in = relu(x@W0 + b), dual-plane ----------------
    for (int job = bid; job < 512; job += nb) {
        int dir = job >> 8, rem = job & 255;
        GDir p = mp.fc[dir];
        gemm512<2, 1, 1, 0>(p.A0, p.Al, p.Wh, p.Wl, p.bias, p.O0,
                            (rem & 63) * 64, (rem >> 6) * 64, SM);
    }
    gg.sync();

    // ---------------- phase MBLO: dual mSA GEMM + masked attention -------------
    {
        short* gAh  = (short*)SM;
        short* gB1h = gAh + 4608;
        short* gB2h = gAh + 9216;
        float* aP   = (float*)SM;
        unsigned int* aQX = (unsigned int*)(SM + 16896);
        int w = tid >> 6, l = tid & 63, m = l & 15, q = l >> 4;
        int rh = w >> 1, cb = (w & 1) * 2;
        int srow = tid >> 3, skl = (tid & 7) * 8;
        for (int job = bid; job < 512; job += nb) {
            int dir = job >> 8, rem = job & 255;
            MbloDir p = mp.mbd[dir];
            int row0 = (rem & 63) * 64, d0 = (rem >> 6) * 64;
            f32x4 acc1[2], acc2[2];
            #pragma unroll
            for (int cf = 0; cf < 2; cf++) { acc1[cf] = (f32x4)(0.f); acc2[cf] = (f32x4)(0.f); }
            for (int kh = 0; kh < 4; kh++) {
                int kbase = kh * 64;
                size_t ga = (size_t)(row0 + srow) * 256 + kbase + skl;
                *(short8*)&gAh[srow * 72 + skl] = *(const short8*)(p.Ah + ga);
                size_t gb = (size_t)(d0 + srow) * 256 + kbase + skl;
                *(short8*)&gB1h[srow * 72 + skl] = *(const short8*)(p.W1h + gb);
                *(short8*)&gB2h[srow * 72 + skl] = *(const short8*)(p.W2h + gb);
                __syncthreads();
                #pragma unroll
                for (int ch = 0; ch < 2; ch++) {
                    int k = ch * 32 + q * 8;
                    short8 ah = *(const short8*)&gAh[(rh * 16 + m) * 72 + k];
                    #pragma unroll
                    for (int cf = 0; cf < 2; cf++) {
                        int bofs = ((cb + cf) * 16 + m) * 72 + k;
                        short8 b1 = *(const short8*)&gB1h[bofs];
                        acc1[cf] = MFMA_B16(ah, b1, acc1[cf]);
                        short8 b2 = *(const short8*)&gB2h[bofs];
                        acc2[cf] = MFMA_B16(ah, b2, acc2[cf]);
                    }
                }
                __syncthreads();
            }
            short* sQX = (short*)aQX;
            #pragma unroll
            for (int cf = 0; cf < 2; cf++) {
                int col = (cb + cf) * 16 + m;
                float mbv = p.mb[d0 + col];
                #pragma unroll
                for (int r = 0; r < 4; r++) {
                    int row = rh * 16 + q * 4 + r;
                    aP[row * 66 + col] = __expf(0.4f * acc1[cf][r]) * KLN;
                    sQX[col * 130 + 2 * row] = f2bs(__expf(0.4f * (acc2[cf][r] + mbv)));
                }
            }
            {
                size_t gx = (size_t)(row0 + srow) * 256 + d0 + skl;
                short8 xh = *(const short8*)(p.Ah + gx);
                #pragma unroll
                for (int t = 0; t < 8; t++)
                    sQX[(skl + t) * 130 + 2 * srow + 1] = xh[t];
            }
            __syncthreads();
            const unsigned int* lane_qx = &aQX[l * 65];
            for (int t8 = 0; t8 < 8; t8++) {
                int i = w + 8 * t8;
                float Pp = aP[i * 66 + l];
                int js = p.fw ? (i + 1) : 0;
                int je = p.fw ? 64 : i;
                float den0 = 0.f, den1 = 0.f, num0 = 0.f, num1 = 0.f;
                int j = js;
                for (; j + 4 <= je; j += 4) {
                    unsigned int u0 = lane_qx[j];
                    unsigned int u1 = lane_qx[j + 1];
                    unsigned int u2 = lane_qx[j + 2];
                    unsigned int u3 = lane_qx[j + 3];
                    float q0 = bs2f((short)(u0 & 0xffff)), x0 = bs2f((short)(u0 >> 16));
                    float q1 = bs2f((short)(u1 & 0xffff)), x1 = bs2f((short)(u1 >> 16));
                    float q2 = bs2f((short)(u2 & 0xffff)), x2 = bs2f((short)(u2 >> 16));
                    float q3 = bs2f((short)(u3 & 0xffff)), x3 = bs2f((short)(u3 >> 16));
                    float w0 = EXP2F(__builtin_amdgcn_rcpf(fmaf(Pp, q0, KLN)));
                    float w1 = EXP2F(__builtin_amdgcn_rcpf(fmaf(Pp, q1, KLN)));
                    float w2 = EXP2F(__builtin_amdgcn_rcpf(fmaf(Pp, q2, KLN)));
                    float w3 = EXP2F(__builtin_amdgcn_rcpf(fmaf(Pp, q3, KLN)));
                    den0 += w0; num0 = fmaf(w0, x0, num0);
                    den1 += w1; num1 = fmaf(w1, x1, num1);
                    den0 += w2; num0 = fmaf(w2, x2, num0);
                    den1 += w3; num1 = fmaf(w3, x3, num1);
                }
                for (; j < je; j++) {
                    unsigned int u0 = lane_qx[j];
                    float q0 = bs2f((short)(u0 & 0xffff)), x0 = bs2f((short)(u0 >> 16));
                    float wgt = EXP2F(__builtin_amdgcn_rcpf(fmaf(Pp, q0, KLN)));
                    den0 += wgt; num0 = fmaf(wgt, x0, num0);
                }
                float den = den0 + den1, num = num0 + num1;
                bool valid = p.fw ? (i < 63) : (i > 0);
                float out = valid ? (num * __builtin_amdgcn_rcpf(den)) : 0.f;
                p.Hh[(size_t)(row0 + i) * 256 + d0 + l] = f2bs(out);
            }
            __syncthreads();
        }
    }
    gg.sync();

    // ---------------- phase S2T1: t1 = relu(h@W3 + b1) -------------------------
    for (int job = bid; job < 512; job += nb) {
        int dir = job >> 8, rem = job & 255;
        GDir p = mp.s2t1[dir];
        gemm512<0, 1, 1, 1>(p.A0, nullptr, p.Wh, nullptr, p.bias, p.O0,
                            (rem & 63) * 64, (rem >> 6) * 64, SM);
    }
    gg.sync();

    // ---------------- phase POOL: L = t1@W4 + b, softmax-pool over rows --------
    {
        short* gAh = (short*)SM;
        short* gBh = gAh + 4608;
        float* aL = (float*)SM;               // 64*68 f32 (overlays gAh/gBh)
        float* aH = aL + 4352;
        float* rm = (float*)(SM + 34816);     // 8*64 *3
        float* rd = rm + 512;
        float* rn = rm + 1024;
        int w = tid >> 6, l = tid & 63, m = l & 15, q = l >> 4;
        int strip = w >> 1, chalf = w & 1;
        int srow = tid >> 3, skl = (tid & 7) * 8;
        for (int job = bid; job < 512; job += nb) {
            int dir = job >> 8, rem = job & 255;
            PoolDir p = mp.pld[dir];
            int row0 = (rem & 63) * 64, d0 = (rem >> 6) * 64;
            f32x4 acc[2];
            acc[0] = (f32x4)(0.f); acc[1] = (f32x4)(0.f);
            for (int kh = 0; kh < 4; kh++) {
                int kbase = kh * 64;
                *(short8*)&gAh[srow * 72 + skl] =
                    *(const short8*)(p.T1 + (size_t)(row0 + srow) * 256 + kbase + skl);
                *(short8*)&gBh[srow * 72 + skl] =
                    *(const short8*)(p.Wh + (size_t)(d0 + srow) * 256 + kbase + skl);
                __syncthreads();
                #pragma unroll
                for (int ch = 0; ch < 2; ch++) {
                    int k = ch * 32 + q * 8;
                    short8 ah = *(const short8*)&gAh[(strip * 16 + m) * 72 + k];
                    #pragma unroll
                    for (int cf = 0; cf < 2; cf++) {
                        short8 bh = *(const short8*)&gBh[((chalf * 2 + cf) * 16 + m) * 72 + k];
                        acc[cf] = MFMA_B16(ah, bh, acc[cf]);
                    }
                }
                __syncthreads();
            }
            #pragma unroll
            for (int cf = 0; cf < 2; cf++) {
                int col = (chalf * 2 + cf) * 16 + m;
                float bv = p.bias[d0 + col];
                #pragma unroll
                for (int r = 0; r < 4; r++) {
                    int row = strip * 16 + q * 4 + r;
                    aL[row * 68 + col] = acc[cf][r] + bv;
                }
            }
            {
                int j = tid >> 3, d8 = (tid & 7) * 8;
                short8 xh = *(const short8*)(p.Hh + (size_t)(row0 + j) * 256 + d0 + d8);
                #pragma unroll
                for (int t = 0; t < 8; t++)
                    aH[j * 68 + d8 + t] = bs2f(xh[t]);
            }
            __syncthreads();
            int dl = tid & 63, rq = tid >> 6;     // 8 chunks of 8 rows
            float mx = -1e30f, den = 0.f, num = 0.f;
            #pragma unroll
            for (int rr = 0; rr < 8; rr++) {
                int r = rq * 8 + rr;
                float lv = aL[r * 68 + dl];
                float hv = aH[r * 68 + dl];
                if (lv > mx) { float sc = __expf(mx - lv); den *= sc; num *= sc; mx = lv; }
                float wgt = __expf(lv - mx);
                den += wgt; num = fmaf(wgt, hv, num);
            }
            rm[rq * 64 + dl] = mx; rd[rq * 64 + dl] = den; rn[rq * 64 + dl] = num;
            __syncthreads();
            if (rq == 0) {
                float M = rm[dl];
                #pragma unroll
                for (int kq = 1; kq < 8; kq++) M = fmaxf(M, rm[kq * 64 + dl]);
                float D = 0.f, Nn = 0.f;
                #pragma unroll
                for (int kq = 0; kq < 8; kq++) {
                    float sc = __expf(rm[kq * 64 + dl] - M);
                    D += rd[kq * 64 + dl] * sc;
                    Nn += rn[kq * 64 + dl] * sc;
                }
                p.V[(size_t)(rem & 63) * 256 + d0 + dl] = Nn / D;
            }
            __syncthreads();
        }
    }
    gg.sync();

    // ---------------- phase ATTN2: level-2 attention + gate --------------------
    {
        float* sVT = (float*)SM;                          // 16384 B
        float (*sPart)[256] = (float(*)[256])(SM + 16384); // 16*256*4
        float* so = (float*)(SM + 32768);
        float* sv = (float*)(SM + 33792);
        float (*red)[64] = (float(*)[64])(SM + 34816);     // 8*64*4
        for (int job = bid; job < 32; job += nb) {
            int b = job & 3, gy = (job >> 2) & 3, dir = job >> 4;
            Gate2Dir p = mp.gtd[dir];
            int k = tid & 255, half = tid >> 8;
            if (p.fw) {
                #pragma unroll
                for (int it = 0; it < 8; it++) {
                    int e = tid + it * 512;
                    int kk = e >> 4, j = e & 15;
                    sVT[e] = p.V[(size_t)(b * 16 + j) * 256 + kk];
                }
                __syncthreads();
                float acc[16];
                #pragma unroll
                for (int j = 0; j < 16; j++) acc[j] = 0.f;
                int kk0 = half * 128;
                #pragma unroll 4
                for (int kk = kk0; kk < kk0 + 128; kk++) {
                    const float4* vr = (const float4*)&sVT[kk * 16];
                    float4 va = vr[0], vb = vr[1], vc = vr[2], vd = vr[3];
                    float w1 = p.W1[(size_t)kk * 256 + k];
                    float w2 = p.W2[(size_t)kk * 256 + k];
                    acc[0]  = fmaf(va.x, w1, acc[0]);
                    acc[1]  = fmaf(va.y, w2, acc[1]);
                    acc[2]  = fmaf(va.z, w2, acc[2]);
                    acc[3]  = fmaf(va.w, w2, acc[3]);
                    acc[4]  = fmaf(vb.x, w2, acc[4]);
                    acc[5]  = fmaf(vb.y, w2, acc[5]);
                    acc[6]  = fmaf(vb.z, w2, acc[6]);
                    acc[7]  = fmaf(vb.w, w2, acc[7]);
                    acc[8]  = fmaf(vc.x, w2, acc[8]);
                    acc[9]  = fmaf(vc.y, w2, acc[9]);
                    acc[10] = fmaf(vc.z, w2, acc[10]);
                    acc[11] = fmaf(vc.w, w2, acc[11]);
                    acc[12] = fmaf(vd.x, w2, acc[12]);
                    acc[13] = fmaf(vd.y, w2, acc[13]);
                    acc[14] = fmaf(vd.z, w2, acc[14]);
                    acc[15] = fmaf(vd.w, w2, acc[15]);
                }
                if (half) {
                    #pragma unroll
                    for (int j = 0; j < 16; j++) sPart[j][k] = acc[j];
                }
                __syncthreads();
                if (!half) {
                    #pragma unroll
                    for (int j = 0; j < 16; j++) acc[j] += sPart[j][k];
                    float base = acc[0] + p.mb[k];
                    float den = 0.f, num = 0.f;
                    #pragma unroll
                    for (int j = 1; j < 16; j++) {
                        float z = (base + acc[j]) * 0.2f;
                        float e2 = __expf(2.f * z);
                        float t = 1.f - 2.f / (e2 + 1.f);
                        float wgt = __expf(5.f * t);
                        den += wgt;
                        num = fmaf(wgt, p.V[(size_t)(b * 16 + j) * 256 + k], num);
                    }
                    so[k] = num / den;
                    sv[k] = p.V[(size_t)(b * 16) * 256 + k];
                }
            } else {
                if (!half) {
                    so[k] = 0.f;
                    sv[k] = p.V[(size_t)(b * 16) * 256 + k];
                }
            }
            __syncthreads();
            int c = tid & 63, ks = tid >> 6;
            int gc = gy * 64 + c;
            float a2 = 0.f;
            int k0 = ks * 32;
            #pragma unroll 8
            for (int kkx = 0; kkx < 32; kkx++) {
                int kx = k0 + kkx;
                a2 += so[kx] * p.gW1[(size_t)kx * 256 + gc] + sv[kx] * p.gW2[(size_t)kx * 256 + gc];
            }
            red[ks][c] = a2;
            __syncthreads();
            if (ks == 0) {
                float a = red[0][c] + red[1][c] + red[2][c] + red[3][c]
                        + red[4][c] + red[5][c] + red[6][c] + red[7][c] + p.gb[gc];
                float G = 1.f / (1.f + __expf(-a));
                p.E0[b * 256 + gc] = G * so[gc] + (1.f - G) * sv[gc];
            }
            __syncthreads();
        }
    }
    gg.sync();

    // ---------------- phase FUSION ---------------------------------------------
    {
        float* cat = (float*)SM;                       // 768 f32
        float (*red1)[64] = (float(*)[64])(SM + 3072); // 8*64
        float (*red2)[64] = (float(*)[64])(SM + 5120);
        for (int job = bid; job < 512; job += nb) {
            int dir = job >> 8, rem = job & 255;
            int bt = rem & 63, gy = rem >> 6;
            FuseDir p = mp.fsd[dir];
            int b = bt >> 4, t = bt & 15;
            size_t xrow = ((size_t)b * 1024 + t) * 256;
            if (tid < 256) {
                cat[tid] = bs2f(p.INh[xrow + tid]);
                cat[512 + tid] = p.E0[b * 256 + tid];
            } else {
                cat[tid] = bs2f(p.Hh[xrow + tid - 256]);
            }
            __syncthreads();
            int c = tid & 63, ks = tid >> 6;           // 8-way k-split x 96
            int gc = gy * 64 + c;
            float a1 = 0.f, a2 = 0.f;
            int k0 = ks * 96;
            #pragma unroll 8
            for (int kk = 0; kk < 96; kk++) {
                int k = k0 + kk;
                float cv = cat[k];
                a1 += cv * p.fW1[(size_t)k * 256 + gc];
                a2 += cv * p.fW2[(size_t)k * 256 + gc];
            }
            red1[ks][c] = a1; red2[ks][c] = a2;
            __syncthreads();
            if (ks == 0) {
                float s1 = p.fb1[gc], s2 = p.fb2[gc];
                #pragma unroll
                for (int kq = 0; kq < 8; kq++) { s1 += red1[kq][c]; s2 += red2[kq][c]; }
                float fus = fmaxf(s1, 0.f);
                float Gf = 1.f / (1.f + __expf(-s2));
                float u = Gf * fus + (1.f - Gf) * cat[gc];
                mp.out[((size_t)(b * 16 + t)) * 512 + (size_t)dir * 256 + gc] = u;
            }
            __syncthreads();
        }
    }
}

// ============================================================================

extern "C" void kernel_launch(void* const* d_in, const int* in_sizes, int n_in,
                              void* d_out, int out_size, void* d_ws, size_t ws_size,
                              hipStream_t stream)
{
    const float* x = (const float*)d_in[0];
    char* base = (char*)d_ws;
    auto alloc = [&](size_t bytes){ void* r = base; base += (bytes + 255) & ~255ULL; return r; };
    short* inH = (short*)alloc(2 * 1048576 * 2);
    short* hH  = (short*)alloc(2 * 1048576 * 2);
    short* t1  = (short*)alloc(2 * 1048576 * 2);
    short* wtH = (short*)alloc(10 * 65536 * 2);
    short* wtL = (short*)alloc(10 * 65536 * 2);
    short* xh  = (short*)alloc(1048576 * 2);
    short* xl  = (short*)alloc(1048576 * 2);
    float* v   = (float*)alloc(2 * 16384 * 4);
    float* E0  = (float*)alloc(2 * 1024 * 4);

    SrcPack sp;
    const int src_idx[5] = {0, 2, 3, 5, 7};  // fcW, mW1, mW2, s2tW1, s2tW
    for (int p = 0; p < 2; p++)
        for (int i = 0; i < 5; i++)
            sp.s[p * 5 + i] = (const float*)d_in[1 + p * 16 + src_idx[i]];

    GDir fc[2], s2t1[2];
    MbloDir mbd[2];
    PoolDir pld[2];
    Gate2Dir gtd[2];
    FuseDir fsd[2];
    for (int p = 0; p < 2; p++) {
        int bi = 1 + p * 16;
        const float* fcb   = (const float*)d_in[bi + 1];
        const float* mb    = (const float*)d_in[bi + 4];
        const float* s2tb1 = (const float*)d_in[bi + 6];
        const float* s2tb  = (const float*)d_in[bi + 8];
        size_t po = (size_t)p * 1048576;
        const short* W0h = wtH + (size_t)(p * 5 + 0) * 65536, *W0l = wtL + (size_t)(p * 5 + 0) * 65536;
        const short* W1h = wtH + (size_t)(p * 5 + 1) * 65536;
        const short* W2h = wtH + (size_t)(p * 5 + 2) * 65536;
        const short* W3h = wtH + (size_t)(p * 5 + 3) * 65536;
        const short* W4h = wtH + (size_t)(p * 5 + 4) * 65536;

        fc[p]   = { xh, xl, W0h, W0l, fcb, inH + po };
        mbd[p]  = { inH + po, W1h, W2h, mb, hH + po, (p == 0) };
        s2t1[p] = { hH + po, nullptr, W3h, nullptr, s2tb1, t1 + po };
        pld[p]  = { t1 + po, W4h, s2tb, hH + po, v + p * 16384 };
        gtd[p]  = { v + p * 16384,
                    (const float*)d_in[bi + 2], (const float*)d_in[bi + 3], mb,
                    (const float*)d_in[bi + 9], (const float*)d_in[bi + 10],
                    (const float*)d_in[bi + 11], E0 + p * 1024, (p == 0) };
        fsd[p]  = { inH + po, hH + po, E0 + p * 1024,
                    (const float*)d_in[bi + 12], (const float*)d_in[bi + 13],
                    (const float*)d_in[bi + 14], (const float*)d_in[bi + 15] };
    }

    // ---- try the cooperative mega-kernel; fall back to the classic chain ----
    static int coopGrid = -2;   // -2 unknown, -1 unavailable, >0 grid size
    if (coopGrid == -2) {
        int perCU = 0;
        hipError_t e1 = hipOccupancyMaxActiveBlocksPerMultiprocessor(&perCU, mega_k, 512, 0);
        if (e1 == hipSuccess && perCU > 0) {
            hipDeviceProp_t prop;
            int dev = 0;
            hipGetDevice(&dev);
            if (hipGetDeviceProperties(&prop, dev) == hipSuccess && prop.cooperativeLaunch) {
                long g = (long)perCU * prop.multiProcessorCount;
                coopGrid = (int)(g > 512 ? 512 : g);
            } else coopGrid = -1;
        } else coopGrid = -1;
    }

    bool done = false;
    if (coopGrid > 0) {
        MegaP mp;
        mp.sp = sp; mp.X = x;
        mp.wtH = wtH; mp.wtL = wtL; mp.xh = xh; mp.xl = xl;
        for (int p = 0; p < 2; p++) {
            mp.fc[p] = fc[p]; mp.s2t1[p] = s2t1[p];
            mp.mbd[p] = mbd[p]; mp.pld[p] = pld[p];
            mp.gtd[p] = gtd[p]; mp.fsd[p] = fsd[p];
        }
        mp.out = (float*)d_out;
        void* kargs[] = { (void*)&mp };
        if (hipLaunchCooperativeKernel((void*)mega_k, dim3(coopGrid), dim3(512),
                                       kargs, 0, stream) == hipSuccess)
            done = true;
        else
            coopGrid = -1;   // don't retry on later calls
    }

    if (!done) {
        prep_k<<<dim3(16, 14), 256, 0, stream>>>(sp, x, wtH, wtL, xh, xl);
        gemm_k<2, 1, 1, 0><<<dim3(64, 4, 2), 256, 0, stream>>>(fc[0], fc[1]);
        mblo_k<<<dim3(128, 4, 2), 512, 0, stream>>>(mbd[0], mbd[1]);
        gemm_k<0, 1, 1, 1><<<dim3(64, 4, 2), 256, 0, stream>>>(s2t1[0], s2t1[1]);
        s2t_pool_k<<<dim3(64, 4, 2), 256, 0, stream>>>(pld[0], pld[1]);
        attn2gate_k<<<dim3(4, 4, 2), 512, 0, stream>>>(gtd[0], gtd[1]);
        fusion_k<<<dim3(64, 4, 2), 256, 0, stream>>>(fsd[0], fsd[1], (float*)d_out);
    }
}

// Round 5
// 207.266 us; speedup vs baseline: 1.0633x; 1.0123x over previous
//
#include <hip/hip_runtime.h>
#include <hip/hip_bf16.h>

typedef __hip_bfloat16 BF16;
typedef __attribute__((ext_vector_type(8))) short short8;
typedef __attribute__((ext_vector_type(4))) float f32x4;

#define MFMA_B16(a,b,c) __builtin_amdgcn_mfma_f32_16x16x32_bf16((a),(b),(c),0,0,0)

#if __has_builtin(__builtin_amdgcn_exp2f)
#define EXP2F(x) __builtin_amdgcn_exp2f(x)
#else
#define EXP2F(x) __expf(0.6931471805599453f * (x))
#endif

__device__ __forceinline__ short f2bs(float f){ BF16 h = __float2bfloat16(f); return *(short*)&h; }
__device__ __forceinline__ float bs2f(short s){ BF16 h = *(BF16*)&s; return __bfloat162float(h); }

// ============================================================================
// K1: fused fc GEMM (self-contained) + W1..W4 hi-plane transposes.
// Jobs 0..511  : fc 64x64 tiles. A = x f32, split hi/lo on the fly (proven
//                AM=1 path); B = raw f32 W0 column-slice, read strided
//                (L2-hot), split hi/lo in-register -> same values and MFMA
//                order as the old prep+GEMM -> bit-identical output.
// Jobs 512..639: n-major bf16 hi-plane transpose of {mW1,mW2,s2tW1,s2tW} x 2
//                dirs (lo planes are dead code since the gemm2s removal).
// LDS 36.9 KB -> 4 blk/CU.
// ============================================================================
struct FcPrepP {
    const float* X;
    const float* W0[2];
    const float* fcb[2];
    short* inH[2];
    const float* wsrc[8];
    short* wdst[8];
};

__global__ __launch_bounds__(256) void fcprep_k(FcPrepP P)
{
    __shared__ char SM[36864] __attribute__((aligned(16)));
    int job = blockIdx.x;
    int tid = threadIdx.x;

    if (job >= 512) {
        // ---- weight transpose, hi plane only ----
        int mi = job - 512;            // 0..127
        int mat = mi >> 4, tile = mi & 15;
        float (*s)[65] = (float(*)[65])SM;   // 64*65*4 = 16640 B
        const float* W = P.wsrc[mat];
        short* oh = P.wdst[mat];
        int tr = (tile >> 2) * 64, tc = (tile & 3) * 64;
        #pragma unroll
        for (int i = 0; i < 16; i++) {
            int e = tid + i * 256;
            int r = e >> 6, c = e & 63;
            s[c][r] = W[(size_t)(tr + r) * 256 + tc + c];
        }
        __syncthreads();
        #pragma unroll
        for (int i = 0; i < 16; i++) {
            int e = tid + i * 256;
            int c2 = e >> 6, r2 = e & 63;
            oh[(size_t)(tc + c2) * 256 + tr + r2] = f2bs(s[c2][r2]);
        }
        return;
    }

    // ---- fc tile ----
    short* sAh = (short*)SM;          // 64*72
    short* sAl = sAh + 4608;
    short* sBh = sAh + 9216;
    short* sBl = sAh + 13824;
    int dir = job >> 8, rem = job & 255;
    int row0 = (rem & 63) * 64, col0 = (rem >> 6) * 64;
    const float* W0 = P.W0[dir];
    const float* bias = P.fcb[dir];
    short* O = P.inH[dir];

    int w = tid >> 6, l = tid & 63;
    int m = l & 15, q = l >> 4;
    int sr = w * 16 + m;
    int bcc = tid >> 2, bkk0 = (tid & 3) * 16;   // B staging map

    f32x4 acc[4];
    #pragma unroll
    for (int cf = 0; cf < 4; cf++) acc[cf] = (f32x4)(0.f);

    for (int kh = 0; kh < 4; kh++) {
        int kbase = kh * 64;
        // A: on-the-fly f32 -> hi/lo (identical to proven AM=1 staging)
        #pragma unroll
        for (int i = 0; i < 2; i++) {
            int kl = q * 8 + 32 * i;
            size_t gofs = (size_t)(row0 + sr) * 256 + kbase + kl;
            const float* src = P.X + gofs;
            float4 f0 = *(const float4*)src;
            float4 f1 = *(const float4*)(src + 4);
            short8 vh, vl;
            float tmp[8] = {f0.x, f0.y, f0.z, f0.w, f1.x, f1.y, f1.z, f1.w};
            #pragma unroll
            for (int j = 0; j < 8; j++) {
                vh[j] = f2bs(tmp[j]);
                vl[j] = f2bs(tmp[j] - bs2f(vh[j]));
            }
            *(short8*)&sAh[sr * 72 + kl] = vh;
            *(short8*)&sAl[sr * 72 + kl] = vl;
        }
        // B: strided raw-f32 column reads (L2-hot), split in-register
        {
            float vals[16];
            #pragma unroll
            for (int j = 0; j < 16; j++)
                vals[j] = W0[(size_t)(kbase + bkk0 + j) * 256 + col0 + bcc];
            #pragma unroll
            for (int h8 = 0; h8 < 2; h8++) {
                short8 vh, vl;
                #pragma unroll
                for (int j = 0; j < 8; j++) {
                    float v = vals[h8 * 8 + j];
                    vh[j] = f2bs(v);
                    vl[j] = f2bs(v - bs2f(vh[j]));
                }
                *(short8*)&sBh[bcc * 72 + bkk0 + h8 * 8] = vh;
                *(short8*)&sBl[bcc * 72 + bkk0 + h8 * 8] = vl;
            }
        }
        __syncthreads();
        #pragma unroll
        for (int ch = 0; ch < 2; ch++) {
            int k = ch * 32 + q * 8;
            short8 ah = *(const short8*)&sAh[(w * 16 + m) * 72 + k];
            short8 al = *(const short8*)&sAl[(w * 16 + m) * 72 + k];
            #pragma unroll
            for (int cf = 0; cf < 4; cf++) {
                short8 bh = *(const short8*)&sBh[(cf * 16 + m) * 72 + k];
                acc[cf] = MFMA_B16(ah, bh, acc[cf]);
                short8 bl = *(const short8*)&sBl[(cf * 16 + m) * 72 + k];
                acc[cf] = MFMA_B16(ah, bl, acc[cf]);
                acc[cf] = MFMA_B16(al, bh, acc[cf]);
            }
        }
        __syncthreads();
    }
    #pragma unroll
    for (int cf = 0; cf < 4; cf++) {
        int col = col0 + cf * 16 + m;
        float bv = bias[col];
        #pragma unroll
        for (int r = 0; r < 4; r++) {
            int row = row0 + w * 16 + q * 4 + r;
            float v = fmaxf(acc[cf][r] + bv, 0.f);
            O[(size_t)row * 256 + col] = f2bs(v);
        }
    }
}

// ============================================================================
// K2: fused dual mSA-GEMM + level-1 masked attention (proven round-0/3 form).
// Grid (128, 4, 2) = 1024 blocks, 512 threads, 33.5 KB LDS -> 4 blk/CU.
// ============================================================================
struct MbloDir { const short* Ah; const short* W1h; const short* W2h;
                 const float* mb; short* Hh; int fw; };

__global__ __launch_bounds__(512) void mblo_k(MbloDir p0, MbloDir p1)
{
    __shared__ char smraw[33536] __attribute__((aligned(16)));
    short* gAh  = (short*)smraw;
    short* gB1h = gAh + 4608;
    short* gB2h = gAh + 9216;
    float* aP   = (float*)smraw;
    unsigned int* aQX = (unsigned int*)(smraw + 16896);

    const float KLN = -0.06931471805599453f;

    MbloDir p = blockIdx.z ? p1 : p0;
    int tid = threadIdx.x;
    int w = tid >> 6, l = tid & 63;
    int m = l & 15, q = l >> 4;
    int rh = w >> 1;
    int cb = (w & 1) * 2;
    int bn = blockIdx.x >> 1, ipar = blockIdx.x & 1;
    int row0 = bn * 64, d0 = blockIdx.y * 64;
    int srow = tid >> 3;
    int skl  = (tid & 7) * 8;

    f32x4 acc1[2], acc2[2];
    #pragma unroll
    for (int cf = 0; cf < 2; cf++) { acc1[cf] = (f32x4)(0.f); acc2[cf] = (f32x4)(0.f); }

    for (int kh = 0; kh < 4; kh++) {
        int kbase = kh * 64;
        size_t ga = (size_t)(row0 + srow) * 256 + kbase + skl;
        *(short8*)&gAh[srow * 72 + skl] = *(const short8*)(p.Ah + ga);
        size_t gb = (size_t)(d0 + srow) * 256 + kbase + skl;
        *(short8*)&gB1h[srow * 72 + skl] = *(const short8*)(p.W1h + gb);
        *(short8*)&gB2h[srow * 72 + skl] = *(const short8*)(p.W2h + gb);
        __syncthreads();
        #pragma unroll
        for (int ch = 0; ch < 2; ch++) {
            int k = ch * 32 + q * 8;
            short8 ah = *(const short8*)&gAh[(rh * 16 + m) * 72 + k];
            #pragma unroll
            for (int cf = 0; cf < 2; cf++) {
                int bofs = ((cb + cf) * 16 + m) * 72 + k;
                short8 b1 = *(const short8*)&gB1h[bofs];
                acc1[cf] = MFMA_B16(ah, b1, acc1[cf]);
                short8 b2 = *(const short8*)&gB2h[bofs];
                acc2[cf] = MFMA_B16(ah, b2, acc2[cf]);
            }
        }
        __syncthreads();
    }
    short* sQX = (short*)aQX;
    #pragma unroll
    for (int cf = 0; cf < 2; cf++) {
        int col = (cb + cf) * 16 + m;
        float mbv = p.mb[d0 + col];
        #pragma unroll
        for (int r = 0; r < 4; r++) {
            int row = rh * 16 + q * 4 + r;
            aP[row * 66 + col] = __expf(0.4f * acc1[cf][r]) * KLN;
            sQX[col * 130 + 2 * row] = f2bs(__expf(0.4f * (acc2[cf][r] + mbv)));
        }
    }
    {
        size_t gx = (size_t)(row0 + srow) * 256 + d0 + skl;
        short8 xh = *(const short8*)(p.Ah + gx);
        #pragma unroll
        for (int t = 0; t < 8; t++)
            sQX[(skl + t) * 130 + 2 * srow + 1] = xh[t];
    }
    __syncthreads();
    const unsigned int* lane_qx = &aQX[l * 65];
    #pragma unroll
    for (int t8 = 0; t8 < 4; t8++) {
        int i = ipar + 2 * (w + 8 * t8);
        float Pp = aP[i * 66 + l];
        int js = p.fw ? (i + 1) : 0;
        int je = p.fw ? 64 : i;
        float den0 = 0.f, den1 = 0.f, num0 = 0.f, num1 = 0.f;
        int j = js;
        for (; j + 4 <= je; j += 4) {
            unsigned int u0 = lane_qx[j];
            unsigned int u1 = lane_qx[j + 1];
            unsigned int u2 = lane_qx[j + 2];
            unsigned int u3 = lane_qx[j + 3];
            float q0 = bs2f((short)(u0 & 0xffff)), x0 = bs2f((short)(u0 >> 16));
            float q1 = bs2f((short)(u1 & 0xffff)), x1 = bs2f((short)(u1 >> 16));
            float q2 = bs2f((short)(u2 & 0xffff)), x2 = bs2f((short)(u2 >> 16));
            float q3 = bs2f((short)(u3 & 0xffff)), x3 = bs2f((short)(u3 >> 16));
            float w0 = EXP2F(__builtin_amdgcn_rcpf(fmaf(Pp, q0, KLN)));
            float w1 = EXP2F(__builtin_amdgcn_rcpf(fmaf(Pp, q1, KLN)));
            float w2 = EXP2F(__builtin_amdgcn_rcpf(fmaf(Pp, q2, KLN)));
            float w3 = EXP2F(__builtin_amdgcn_rcpf(fmaf(Pp, q3, KLN)));
            den0 += w0; num0 = fmaf(w0, x0, num0);
            den1 += w1; num1 = fmaf(w1, x1, num1);
            den0 += w2; num0 = fmaf(w2, x2, num0);
            den1 += w3; num1 = fmaf(w3, x3, num1);
        }
        for (; j < je; j++) {
            unsigned int u0 = lane_qx[j];
            float q0 = bs2f((short)(u0 & 0xffff)), x0 = bs2f((short)(u0 >> 16));
            float wgt = EXP2F(__builtin_amdgcn_rcpf(fmaf(Pp, q0, KLN)));
            den0 += wgt; num0 = fmaf(wgt, x0, num0);
        }
        float den = den0 + den1, num = num0 + num1;
        bool valid = p.fw ? (i < 63) : (i > 0);
        float out = valid ? (num * __builtin_amdgcn_rcpf(den)) : 0.f;
        p.Hh[(size_t)(row0 + i) * 256 + d0 + l] = f2bs(out);
    }
}

// ============================================================================
// K3: fused s2t (T1 in LDS) + logits GEMM + softmax pool (proven round-2 form).
// Grid (64, 4, 2) = 1024 blocks, 512 threads, 78 KB LDS -> 2 blk/CU.
// ============================================================================
struct S2TDir { const short* Hh; const short* W3h; const float* b1;
                const short* W4h; const float* b2; float* V; };

__global__ __launch_bounds__(512) void s2t_fused_k(S2TDir p0, S2TDir p1)
{
    __shared__ char smraw[79872] __attribute__((aligned(16)));
    short* sT1 = (short*)smraw;
    short* gA  = (short*)(smraw + 33792);
    short* gB  = (short*)(smraw + 43008);
    short* gB2 = (short*)(smraw + 33792);
    float* aL  = (float*)(smraw + 43008);
    float* rm  = (float*)(smraw + 60416);
    float* rd  = rm + 512;
    float* rn  = rm + 1024;

    S2TDir p = blockIdx.z ? p1 : p0;
    int tid = threadIdx.x;
    int w = tid >> 6, l = tid & 63;
    int m = l & 15, q = l >> 4;
    int row0 = blockIdx.x * 64;
    int d0 = blockIdx.y * 64;
    int strip = w >> 1, chalf = w & 1;
    int srow = tid >> 3, skl = (tid & 7) * 8;

    f32x4 acc1[8];
    #pragma unroll
    for (int cf = 0; cf < 8; cf++) acc1[cf] = (f32x4)(0.f);
    for (int kh = 0; kh < 4; kh++) {
        int kbase = kh * 64;
        *(short8*)&gA[srow * 72 + skl] =
            *(const short8*)(p.Hh + (size_t)(row0 + srow) * 256 + kbase + skl);
        int bn = tid >> 1;
        #pragma unroll
        for (int i = 0; i < 4; i++) {
            int kseg = (tid & 1) * 32 + i * 8;
            *(short8*)&gB[bn * 72 + kseg] =
                *(const short8*)(p.W3h + (size_t)bn * 256 + kbase + kseg);
        }
        __syncthreads();
        #pragma unroll
        for (int ch = 0; ch < 2; ch++) {
            int k = ch * 32 + q * 8;
            short8 ah = *(const short8*)&gA[(strip * 16 + m) * 72 + k];
            #pragma unroll
            for (int cf = 0; cf < 8; cf++) {
                short8 bh = *(const short8*)&gB[(chalf * 128 + cf * 16 + m) * 72 + k];
                acc1[cf] = MFMA_B16(ah, bh, acc1[cf]);
            }
        }
        __syncthreads();
    }
    #pragma unroll
    for (int cf = 0; cf < 8; cf++) {
        int col = chalf * 128 + cf * 16 + m;
        float bv = p.b1[col];
        #pragma unroll
        for (int r = 0; r < 4; r++) {
            int row = strip * 16 + q * 4 + r;
            sT1[row * 264 + col] = f2bs(fmaxf(acc1[cf][r] + bv, 0.f));
        }
    }
    __syncthreads();

    f32x4 acc2[2];
    acc2[0] = (f32x4)(0.f); acc2[1] = (f32x4)(0.f);
    for (int kh = 0; kh < 4; kh++) {
        int kbase = kh * 64;
        *(short8*)&gB2[srow * 72 + skl] =
            *(const short8*)(p.W4h + (size_t)(d0 + srow) * 256 + kbase + skl);
        __syncthreads();
        #pragma unroll
        for (int ch = 0; ch < 2; ch++) {
            int k = ch * 32 + q * 8;
            short8 ah = *(const short8*)&sT1[(strip * 16 + m) * 264 + kbase + k];
            #pragma unroll
            for (int cf = 0; cf < 2; cf++) {
                short8 bh = *(const short8*)&gB2[(chalf * 32 + cf * 16 + m) * 72 + k];
                acc2[cf] = MFMA_B16(ah, bh, acc2[cf]);
            }
        }
        __syncthreads();
    }
    #pragma unroll
    for (int cf = 0; cf < 2; cf++) {
        int col = chalf * 32 + cf * 16 + m;
        float bv = p.b2[d0 + col];
        #pragma unroll
        for (int r = 0; r < 4; r++) {
            int row = strip * 16 + q * 4 + r;
            aL[row * 68 + col] = acc2[cf][r] + bv;
        }
    }
    __syncthreads();
    int dl = tid & 63, rq = tid >> 6;
    float mx = -1e30f, den = 0.f, num = 0.f;
    #pragma unroll
    for (int rr = 0; rr < 8; rr++) {
        int r = rq * 8 + rr;
        float lv = aL[r * 68 + dl];
        float hv = bs2f(p.Hh[(size_t)(row0 + r) * 256 + d0 + dl]);
        if (lv > mx) { float sc = __expf(mx - lv); den *= sc; num *= sc; mx = lv; }
        float wgt = __expf(lv - mx);
        den += wgt; num = fmaf(wgt, hv, num);
    }
    rm[rq * 64 + dl] = mx; rd[rq * 64 + dl] = den; rn[rq * 64 + dl] = num;
    __syncthreads();
    if (rq == 0) {
        float M = rm[dl];
        #pragma unroll
        for (int kq = 1; kq < 8; kq++) M = fmaxf(M, rm[kq * 64 + dl]);
        float D = 0.f, Nn = 0.f;
        #pragma unroll
        for (int kq = 0; kq < 8; kq++) {
            float sc = __expf(rm[kq * 64 + dl] - M);
            D += rd[kq * 64 + dl] * sc;
            Nn += rn[kq * 64 + dl] * sc;
        }
        p.V[(size_t)blockIdx.x * 256 + d0 + dl] = Nn / D;
    }
}

// ============================================================================
// K4: fused level-2 attention + gate with inline f32 GEMV (proven round-3).
// ============================================================================
struct Gate2Dir { const float* V; const float* W1; const float* W2; const float* mb;
                  const float* gW1; const float* gW2; const float* gb;
                  float* E0; int fw; };

__global__ __launch_bounds__(512) void attn2gate_k(Gate2Dir p0, Gate2Dir p1)
{
    Gate2Dir p = blockIdx.z ? p1 : p0;
    __shared__ __attribute__((aligned(16))) float sVT[4096];
    __shared__ float sPart[16][256];
    __shared__ float so[256], sv[256], red[8][64];
    int tid = threadIdx.x;
    int b = blockIdx.x;
    int k = tid & 255, half = tid >> 8;

    if (p.fw) {
        #pragma unroll
        for (int it = 0; it < 8; it++) {
            int e = tid + it * 512;
            int kk = e >> 4, j = e & 15;
            sVT[e] = p.V[(size_t)(b * 16 + j) * 256 + kk];
        }
        __syncthreads();
        float acc[16];
        #pragma unroll
        for (int j = 0; j < 16; j++) acc[j] = 0.f;
        int kk0 = half * 128;
        #pragma unroll 4
        for (int kk = kk0; kk < kk0 + 128; kk++) {
            const float4* vr = (const float4*)&sVT[kk * 16];
            float4 va = vr[0], vb = vr[1], vc = vr[2], vd = vr[3];
            float w1 = p.W1[(size_t)kk * 256 + k];
            float w2 = p.W2[(size_t)kk * 256 + k];
            acc[0]  = fmaf(va.x, w1, acc[0]);
            acc[1]  = fmaf(va.y, w2, acc[1]);
            acc[2]  = fmaf(va.z, w2, acc[2]);
            acc[3]  = fmaf(va.w, w2, acc[3]);
            acc[4]  = fmaf(vb.x, w2, acc[4]);
            acc[5]  = fmaf(vb.y, w2, acc[5]);
            acc[6]  = fmaf(vb.z, w2, acc[6]);
            acc[7]  = fmaf(vb.w, w2, acc[7]);
            acc[8]  = fmaf(vc.x, w2, acc[8]);
            acc[9]  = fmaf(vc.y, w2, acc[9]);
            acc[10] = fmaf(vc.z, w2, acc[10]);
            acc[11] = fmaf(vc.w, w2, acc[11]);
            acc[12] = fmaf(vd.x, w2, acc[12]);
            acc[13] = fmaf(vd.y, w2, acc[13]);
            acc[14] = fmaf(vd.z, w2, acc[14]);
            acc[15] = fmaf(vd.w, w2, acc[15]);
        }
        if (half) {
            #pragma unroll
            for (int j = 0; j < 16; j++) sPart[j][k] = acc[j];
        }
        __syncthreads();
        if (!half) {
            #pragma unroll
            for (int j = 0; j < 16; j++) acc[j] += sPart[j][k];
            float base = acc[0] + p.mb[k];
            float den = 0.f, num = 0.f;
            #pragma unroll
            for (int j = 1; j < 16; j++) {
                float z = (base + acc[j]) * 0.2f;
                float e2 = __expf(2.f * z);
                float t = 1.f - 2.f / (e2 + 1.f);
                float wgt = __expf(5.f * t);
                den += wgt;
                num = fmaf(wgt, p.V[(size_t)(b * 16 + j) * 256 + k], num);
            }
            so[k] = num / den;
            sv[k] = p.V[(size_t)(b * 16) * 256 + k];
        }
    } else {
        if (!half) {
            so[k] = 0.f;
            sv[k] = p.V[(size_t)(b * 16) * 256 + k];
        }
    }
    __syncthreads();
    int c = tid & 63, ks = tid >> 6;
    int gc = blockIdx.y * 64 + c;
    float a2 = 0.f;
    int k0 = ks * 32;
    #pragma unroll 8
    for (int kkx = 0; kkx < 32; kkx++) {
        int kx = k0 + kkx;
        a2 += so[kx] * p.gW1[(size_t)kx * 256 + gc] + sv[kx] * p.gW2[(size_t)kx * 256 + gc];
    }
    red[ks][c] = a2;
    __syncthreads();
    if (ks == 0) {
        float a = red[0][c] + red[1][c] + red[2][c] + red[3][c]
                + red[4][c] + red[5][c] + red[6][c] + red[7][c] + p.gb[gc];
        float G = 1.f / (1.f + __expf(-a));
        p.E0[b * 256 + gc] = G * so[gc] + (1.f - G) * sv[gc];
    }
}

// ============================================================================
// K5: fusion (proven).
// ============================================================================
struct FuseDir { const short* INh; const short* Hh;
                 const float* E0; const float* fW1; const float* fb1;
                 const float* fW2; const float* fb2; };

__global__ __launch_bounds__(256) void fusion_k(FuseDir p0, FuseDir p1, float* __restrict__ out)
{
    FuseDir p = blockIdx.z ? p1 : p0;
    __shared__ float cat[768];
    __shared__ float red1[4][64], red2[4][64];
    int bt = blockIdx.x, b = bt >> 4, t = bt & 15;
    int c = threadIdx.x & 63, ks = threadIdx.x >> 6;
    int gc = blockIdx.y * 64 + c;
    size_t xrow = ((size_t)b * 1024 + t) * 256;
    cat[threadIdx.x]       = bs2f(p.INh[xrow + threadIdx.x]);
    cat[256 + threadIdx.x] = bs2f(p.Hh[xrow + threadIdx.x]);
    cat[512 + threadIdx.x] = p.E0[b * 256 + threadIdx.x];
    __syncthreads();
    float a1 = 0.f, a2 = 0.f;
    int k0 = ks * 192;
    #pragma unroll 8
    for (int kk = 0; kk < 192; kk++) {
        int k = k0 + kk;
        float cv = cat[k];
        a1 += cv * p.fW1[(size_t)k * 256 + gc];
        a2 += cv * p.fW2[(size_t)k * 256 + gc];
    }
    red1[ks][c] = a1; red2[ks][c] = a2;
    __syncthreads();
    if (ks == 0) {
        float s1 = red1[0][c] + red1[1][c] + red1[2][c] + red1[3][c] + p.fb1[gc];
        float s2 = red2[0][c] + red2[1][c] + red2[2][c] + red2[3][c] + p.fb2[gc];
        float fus = fmaxf(s1, 0.f);
        float Gf = 1.f / (1.f + __expf(-s2));
        float u = Gf * fus + (1.f - Gf) * cat[gc];
        out[((size_t)(b * 16 + t)) * 512 + (size_t)blockIdx.z * 256 + gc] = u;
    }
}

extern "C" void kernel_launch(void* const* d_in, const int* in_sizes, int n_in,
                              void* d_out, int out_size, void* d_ws, size_t ws_size,
                              hipStream_t stream)
{
    const float* x = (const float*)d_in[0];
    char* base = (char*)d_ws;
    auto alloc = [&](size_t bytes){ void* r = base; base += (bytes + 255) & ~255ULL; return r; };
    short* inH = (short*)alloc(2 * 1048576 * 2);
    short* hH  = (short*)alloc(2 * 1048576 * 2);
    short* wtH = (short*)alloc(10 * 65536 * 2);
    float* v   = (float*)alloc(2 * 16384 * 4);
    float* E0  = (float*)alloc(2 * 1024 * 4);

    FcPrepP fp;
    fp.X = x;
    const int wsrc_idx[4] = {2, 3, 5, 7};      // mW1, mW2, s2tW1, s2tW
    for (int p = 0; p < 2; p++) {
        int bi = 1 + p * 16;
        fp.W0[p]  = (const float*)d_in[bi + 0];
        fp.fcb[p] = (const float*)d_in[bi + 1];
        fp.inH[p] = inH + (size_t)p * 1048576;
        for (int wi = 0; wi < 4; wi++) {
            fp.wsrc[p * 4 + wi] = (const float*)d_in[bi + wsrc_idx[wi]];
            fp.wdst[p * 4 + wi] = wtH + (size_t)(p * 5 + 1 + wi) * 65536;
        }
    }

    MbloDir mbd[2];
    S2TDir std_[2];
    Gate2Dir gtd[2];
    FuseDir fsd[2];
    for (int p = 0; p < 2; p++) {
        int bi = 1 + p * 16;
        const float* mb    = (const float*)d_in[bi + 4];
        const float* s2tb1 = (const float*)d_in[bi + 6];
        const float* s2tb  = (const float*)d_in[bi + 8];
        size_t po = (size_t)p * 1048576;
        const short* W1h = wtH + (size_t)(p * 5 + 1) * 65536;
        const short* W2h = wtH + (size_t)(p * 5 + 2) * 65536;
        const short* W3h = wtH + (size_t)(p * 5 + 3) * 65536;
        const short* W4h = wtH + (size_t)(p * 5 + 4) * 65536;

        mbd[p]  = { inH + po, W1h, W2h, mb, hH + po, (p == 0) };
        std_[p] = { hH + po, W3h, s2tb1, W4h, s2tb, v + p * 16384 };
        gtd[p]  = { v + p * 16384,
                    (const float*)d_in[bi + 2], (const float*)d_in[bi + 3], mb,
                    (const float*)d_in[bi + 9], (const float*)d_in[bi + 10],
                    (const float*)d_in[bi + 11], E0 + p * 1024, (p == 0) };
        fsd[p]  = { inH + po, hH + po, E0 + p * 1024,
                    (const float*)d_in[bi + 12], (const float*)d_in[bi + 13],
                    (const float*)d_in[bi + 14], (const float*)d_in[bi + 15] };
    }

    fcprep_k<<<dim3(640), 256, 0, stream>>>(fp);
    mblo_k<<<dim3(128, 4, 2), 512, 0, stream>>>(mbd[0], mbd[1]);
    s2t_fused_k<<<dim3(64, 4, 2), 512, 0, stream>>>(std_[0], std_[1]);
    attn2gate_k<<<dim3(4, 4, 2), 512, 0, stream>>>(gtd[0], gtd[1]);
    fusion_k<<<dim3(64, 4, 2), 256, 0, stream>>>(fsd[0], fsd[1], (float*)d_out);
}